// Round 2
// baseline (354.157 us; speedup 1.0000x reference)
//
#include <hip/hip_runtime.h>

#define SEQ    2048
#define DMODEL 1024
#define NHEAD  16
#define DHEAD  64
#define NBATCH 2

typedef __bf16 bf16x8 __attribute__((ext_vector_type(8)));
typedef float f32x16 __attribute__((ext_vector_type(16)));
typedef unsigned short ushort8v __attribute__((ext_vector_type(8)));
typedef unsigned short ushort4v __attribute__((ext_vector_type(4)));
typedef int int4v __attribute__((ext_vector_type(4)));

static __device__ __forceinline__ unsigned short f2b(float f){
  unsigned int u = __builtin_bit_cast(unsigned int, f);
  u += 0x7fffu + ((u>>16)&1u);            // RNE to bf16
  return (unsigned short)(u>>16);
}
static __device__ __forceinline__ float b2f(unsigned short h){
  unsigned int u = ((unsigned int)h)<<16;
  return __builtin_bit_cast(float, u);
}
static __device__ __forceinline__ unsigned int pk2(float lo, float hi){
  return (unsigned int)f2b(lo) | ((unsigned int)f2b(hi)<<16);
}
static __device__ __forceinline__ f32x16 mfma32(bf16x8 a, bf16x8 b, f32x16 c){
  return __builtin_amdgcn_mfma_f32_32x32x16_bf16(a,b,c,0,0,0);
}

// ---------- A transpose + convert: At[q][k] = bf16(A[k][q]) ----------
__global__ __launch_bounds__(256) void cvtA(const float* __restrict__ A,
                                            unsigned short* __restrict__ At){
  __shared__ float T[64][65];
  const int tid = threadIdx.x;
  const int rb = blockIdx.y*64;   // k rows of A
  const int cb = blockIdx.x*64;   // q cols of A
  const int r = tid>>2, c0 = (tid&3)*16;
  const float* ap = A + (size_t)(rb+r)*SEQ + cb + c0;
  #pragma unroll
  for (int i=0;i<4;i++){
    float4 f = *(const float4*)(ap + 4*i);
    T[r][c0+4*i+0] = f.x; T[r][c0+4*i+1] = f.y;
    T[r][c0+4*i+2] = f.z; T[r][c0+4*i+3] = f.w;
  }
  __syncthreads();
  unsigned short tmp[16];
  #pragma unroll
  for (int j=0;j<16;j++) tmp[j] = f2b(T[c0+j][r]);
  ushort8v w0, w1;
  #pragma unroll
  for (int j=0;j<8;j++){ w0[j] = tmp[j]; w1[j] = tmp[8+j]; }
  unsigned short* dst = At + (size_t)(cb + r)*SEQ + rb + c0;
  *(ushort8v*)dst = w0;
  *(ushort8v*)(dst+8) = w1;
}

// ---------- fused q/k/v projection: Y = (X*W^T + b)*alpha, head layout ----------
// z==2 (V) writes TRANSPOSED per head: vt[(bh*DHEAD + dk)*SEQ + s]
__global__ __launch_bounds__(256) void proj_qkv(
    const float* __restrict__ qx, const float* __restrict__ kx, const float* __restrict__ vx,
    const float* __restrict__ Wq, const float* __restrict__ Wk, const float* __restrict__ Wv,
    const float* __restrict__ bq, const float* __restrict__ bk, const float* __restrict__ bv,
    unsigned short* __restrict__ qh, unsigned short* __restrict__ kh, unsigned short* __restrict__ vt)
{
  const int z = blockIdx.z;
  const float* X    = (z==0)? qx : (z==1)? kx : vx;
  const float* W    = (z==0)? Wq : (z==1)? Wk : Wv;
  const float* bias = (z==0)? bq : (z==1)? bk : bv;
  const float alpha = (z==0)? 0.125f : 1.0f;   // fold 1/sqrt(DK) into qh

  const int mb = blockIdx.y*128, nb = blockIdx.x*128;
  __shared__ unsigned short Xs[128][72];
  __shared__ unsigned short Ws[128][72];
  const int tid = threadIdx.x;
  const int lane = tid&63, wave = tid>>6;
  const int wr = wave>>1, wc = wave&1, l31 = lane&31, hi = lane>>5;
  f32x16 acc[2][2] = {};
  const int sr = tid>>1, sh = (tid&1)*32;

  for (int kb=0; kb<DMODEL; kb+=64){
    const float* xrow = X + (size_t)(mb+sr)*DMODEL + kb + sh;
    const float* wrow = W + (size_t)(nb+sr)*DMODEL + kb + sh;
    #pragma unroll
    for (int c=0;c<4;c++){
      float4 a0 = *(const float4*)(xrow + 8*c);
      float4 a1 = *(const float4*)(xrow + 8*c + 4);
      int4v px; px.x = pk2(a0.x,a0.y); px.y = pk2(a0.z,a0.w);
                px.z = pk2(a1.x,a1.y); px.w = pk2(a1.z,a1.w);
      *(int4v*)&Xs[sr][sh + 8*c] = px;
      float4 b0 = *(const float4*)(wrow + 8*c);
      float4 b1 = *(const float4*)(wrow + 8*c + 4);
      int4v pw; pw.x = pk2(b0.x,b0.y); pw.y = pk2(b0.z,b0.w);
                pw.z = pk2(b1.x,b1.y); pw.w = pk2(b1.z,b1.w);
      *(int4v*)&Ws[sr][sh + 8*c] = pw;
    }
    __syncthreads();
    #pragma unroll
    for (int s=0;s<4;s++){
      bf16x8 a0 = *(const bf16x8*)&Xs[64*wr +      l31][16*s + 8*hi];
      bf16x8 a1 = *(const bf16x8*)&Xs[64*wr + 32 + l31][16*s + 8*hi];
      bf16x8 b0 = *(const bf16x8*)&Ws[64*wc +      l31][16*s + 8*hi];
      bf16x8 b1 = *(const bf16x8*)&Ws[64*wc + 32 + l31][16*s + 8*hi];
      acc[0][0] = mfma32(a0,b0,acc[0][0]);
      acc[0][1] = mfma32(a0,b1,acc[0][1]);
      acc[1][0] = mfma32(a1,b0,acc[1][0]);
      acc[1][1] = mfma32(a1,b1,acc[1][1]);
    }
    __syncthreads();
  }
  #pragma unroll
  for (int fj=0; fj<2; fj++){
    const int e = nb + 64*wc + 32*fj + l31;
    const float bv_ = bias[e];
    const int hh = e>>6, dk = e&63;
    #pragma unroll
    for (int fi=0; fi<2; fi++){
      #pragma unroll
      for (int r=0;r<16;r++){
        const int i = mb + 64*wr + 32*fi + (r&3) + 8*(r>>2) + 4*hi;
        const int bb = i>>11, ss = i&(SEQ-1);
        const unsigned short val = f2b((acc[fi][fj][r] + bv_)*alpha);
        if (z==2){
          vt[((size_t)((bb*NHEAD + hh)*DHEAD + dk))*SEQ + ss] = val;
        } else {
          unsigned short* Y = (z==0)? qh : kh;
          Y[((size_t)((bb*NHEAD + hh)*SEQ + ss))*DHEAD + dk] = val;
        }
      }
    }
  }
}

// ---------- fused masked attention: x = (Qh Kh^T ∘ A^T) Vh ----------
// barrier-free k-loop; 4 waves = 2 q-subtiles x 2 k-halves; LDS reduce at end
__global__ __launch_bounds__(256,4) void attn(
    const unsigned short* __restrict__ qh, const unsigned short* __restrict__ kh,
    const unsigned short* __restrict__ vt, const unsigned short* __restrict__ At,
    unsigned short* __restrict__ xbuf)
{
  const int qblk = blockIdx.x;     // 0..31  (64 q-rows per block)
  const int bh   = blockIdx.y;     // 0..31
  const int tid  = threadIdx.x;
  const int lane = tid&63, wave = tid>>6;
  const int qsub = wave&1, khalf = wave>>1;
  const int l31 = lane&31, hi = lane>>5;
  const size_t hb  = (size_t)bh * SEQ * DHEAD;
  const size_t vbb = (size_t)bh * DHEAD * SEQ;

  const int qrow = qblk*64 + qsub*32 + l31;
  const unsigned short* qp = qh + hb + (size_t)qrow*DHEAD;
  bf16x8 Qf[4];
  #pragma unroll
  for (int t=0;t<4;t++) Qf[t] = *(const bf16x8*)(qp + 16*t + 8*hi);

  f32x16 xacc[2] = {};
  const unsigned short* arow  = At + (size_t)qrow*SEQ;
  const unsigned short* vrow0 = vt + vbb + (size_t)l31*SEQ;
  const unsigned short* vrow1 = vrow0 + (size_t)32*SEQ;

  for (int t=0; t<16; t++){
    const int kb = (khalf*16 + t)*64;
    // scores^T = K * Q^T (scale pre-folded into qh)
    f32x16 sacc[2] = {};
    const unsigned short* kp = kh + hb + (size_t)(kb + l31)*DHEAD;
    #pragma unroll
    for (int s=0;s<4;s++){
      bf16x8 k0 = *(const bf16x8*)(kp + 16*s + 8*hi);
      bf16x8 k1 = *(const bf16x8*)(kp + 32*DHEAD + 16*s + 8*hi);
      sacc[0] = mfma32(k0, Qf[s], sacc[0]);
      sacc[1] = mfma32(k1, Qf[s], sacc[1]);
    }
    // mask multiply (P^T[k][q] *= A[k][q]) + pack to bf16 pairs along k
    unsigned int wv[2][4], xv[2][4];
    #pragma unroll
    for (int fi=0; fi<2; fi++){
      #pragma unroll
      for (int mm=0; mm<4; mm++){
        ushort4v a4 = *(const ushort4v*)(arow + kb + 32*fi + 8*mm + 4*hi);
        const int rb2 = 4*mm;
        float p0 = sacc[fi][rb2+0]*b2f(a4[0]);
        float p1 = sacc[fi][rb2+1]*b2f(a4[1]);
        float p2 = sacc[fi][rb2+2]*b2f(a4[2]);
        float p3 = sacc[fi][rb2+3]*b2f(a4[3]);
        wv[fi][mm] = pk2(p0,p1);
        xv[fi][mm] = pk2(p2,p3);
      }
    }
    // x += P * V  (P A-operand assembled in-register; V^T read direct from L2)
    #pragma unroll
    for (int s2=0; s2<4; s2++){
      const int fi = s2>>1, sl = s2&1;
      unsigned int pw = __shfl_xor(hi ? wv[fi][2*sl] : wv[fi][2*sl+1], 32, 64);
      unsigned int px = __shfl_xor(hi ? xv[fi][2*sl] : xv[fi][2*sl+1], 32, 64);
      int4v av;
      av.x = (int)(hi ? pw : wv[fi][2*sl]);
      av.y = (int)(hi ? px : xv[fi][2*sl]);
      av.z = (int)(hi ? wv[fi][2*sl+1] : pw);
      av.w = (int)(hi ? xv[fi][2*sl+1] : px);
      bf16x8 pa = __builtin_bit_cast(bf16x8, av);
      bf16x8 v0 = *(const bf16x8*)(vrow0 + kb + 16*s2 + 8*hi);
      bf16x8 v1 = *(const bf16x8*)(vrow1 + kb + 16*s2 + 8*hi);
      xacc[0] = mfma32(pa, v0, xacc[0]);
      xacc[1] = mfma32(pa, v1, xacc[1]);
    }
  }

  // cross-wave split-K reduction (single barrier)
  __shared__ float Red[2][64][33];
  if (khalf==1){
    #pragma unroll
    for (int j=0;j<2;j++)
      #pragma unroll
      for (int r=0;r<16;r++)
        Red[qsub][lane][16*j+r] = xacc[j][r];
  }
  __syncthreads();
  if (khalf==0){
    #pragma unroll
    for (int j=0;j<2;j++)
      #pragma unroll
      for (int r=0;r<16;r++)
        xacc[j][r] += Red[qsub][lane][16*j+r];
    const int b = bh>>4, h = bh&15;
    #pragma unroll
    for (int fj=0; fj<2; fj++){
      #pragma unroll
      for (int r=0;r<16;r++){
        const int qq = qblk*64 + qsub*32 + (r&3) + 8*(r>>2) + 4*hi;
        const int dd = 32*fj + l31;
        xbuf[((size_t)(b*SEQ + qq))*DMODEL + h*DHEAD + dd] = f2b(xacc[fj][r]);
      }
    }
  }
}

// ---------- output projection: out = x * Wo^T + bo (fp32 out) ----------
__global__ __launch_bounds__(256) void oproj(
    const unsigned short* __restrict__ xb, const float* __restrict__ Wo,
    const float* __restrict__ bo, float* __restrict__ out)
{
  const int mb = blockIdx.y*128, nb = blockIdx.x*128;
  __shared__ unsigned short Xs[128][72];
  __shared__ unsigned short Ws[128][72];
  const int tid = threadIdx.x;
  const int lane = tid&63, wave = tid>>6;
  const int wr = wave>>1, wc = wave&1, l31 = lane&31, hi = lane>>5;
  f32x16 acc[2][2] = {};
  const int sr = tid>>1, sh = (tid&1)*32;
  for (int kb=0; kb<DMODEL; kb+=64){
    const unsigned short* xrow = xb + (size_t)(mb+sr)*DMODEL + kb + sh;
    const float* wrow = Wo + (size_t)(nb+sr)*DMODEL + kb + sh;
    #pragma unroll
    for (int c=0;c<4;c++){
      *(ushort8v*)&Xs[sr][sh + 8*c] = *(const ushort8v*)(xrow + 8*c);
      float4 b0 = *(const float4*)(wrow + 8*c);
      float4 b1 = *(const float4*)(wrow + 8*c + 4);
      int4v pw; pw.x = pk2(b0.x,b0.y); pw.y = pk2(b0.z,b0.w);
                pw.z = pk2(b1.x,b1.y); pw.w = pk2(b1.z,b1.w);
      *(int4v*)&Ws[sr][sh + 8*c] = pw;
    }
    __syncthreads();
    #pragma unroll
    for (int s=0;s<4;s++){
      bf16x8 a0 = *(const bf16x8*)&Xs[64*wr +      l31][16*s + 8*hi];
      bf16x8 a1 = *(const bf16x8*)&Xs[64*wr + 32 + l31][16*s + 8*hi];
      bf16x8 b0 = *(const bf16x8*)&Ws[64*wc +      l31][16*s + 8*hi];
      bf16x8 b1 = *(const bf16x8*)&Ws[64*wc + 32 + l31][16*s + 8*hi];
      acc[0][0] = mfma32(a0,b0,acc[0][0]);
      acc[0][1] = mfma32(a0,b1,acc[0][1]);
      acc[1][0] = mfma32(a1,b0,acc[1][0]);
      acc[1][1] = mfma32(a1,b1,acc[1][1]);
    }
    __syncthreads();
  }
  #pragma unroll
  for (int fj=0; fj<2; fj++){
    const int e = nb + 64*wc + 32*fj + l31;
    const float bv_ = bo[e];
    #pragma unroll
    for (int fi=0; fi<2; fi++){
      #pragma unroll
      for (int r=0;r<16;r++){
        const int i = mb + 64*wr + 32*fi + (r&3) + 8*(r>>2) + 4*hi;
        out[(size_t)i*DMODEL + e] = acc[fi][fj][r] + bv_;
      }
    }
  }
}

extern "C" void kernel_launch(void* const* d_in, const int* in_sizes, int n_in,
                              void* d_out, int out_size, void* d_ws, size_t ws_size,
                              hipStream_t stream)
{
  const float* q  = (const float*)d_in[0];
  const float* k  = (const float*)d_in[1];
  const float* v  = (const float*)d_in[2];
  const float* A  = (const float*)d_in[3];
  const float* Wq = (const float*)d_in[4];
  const float* bq = (const float*)d_in[5];
  const float* Wk = (const float*)d_in[6];
  const float* bk = (const float*)d_in[7];
  const float* Wv = (const float*)d_in[8];
  const float* bv = (const float*)d_in[9];
  const float* Wo = (const float*)d_in[10];
  const float* bo = (const float*)d_in[11];
  float* out = (float*)d_out;

  // workspace layout (bf16 elements): qh, kh, vt, x, A^T  -> 5 * 8MB = 40MB
  unsigned short* ws = (unsigned short*)d_ws;
  const size_t NE = (size_t)NBATCH*SEQ*DMODEL;   // 4M elements
  unsigned short* qh = ws;
  unsigned short* kh = qh + NE;
  unsigned short* vt = kh + NE;
  unsigned short* xb = vt + NE;
  unsigned short* At = xb + NE;

  cvtA<<<dim3(SEQ/64, SEQ/64), 256, 0, stream>>>(A, At);
  proj_qkv<<<dim3(DMODEL/128, (NBATCH*SEQ)/128, 3), 256, 0, stream>>>(
      q,k,v, Wq,Wk,Wv, bq,bk,bv, qh,kh,vt);
  attn<<<dim3(SEQ/64, NBATCH*NHEAD), 256, 0, stream>>>(qh, kh, vt, At, xb);
  oproj<<<dim3(DMODEL/128, (NBATCH*SEQ)/128), 256, 0, stream>>>(xb, Wo, bo, out);
}

// Round 3
// 249.608 us; speedup vs baseline: 1.4188x; 1.4188x over previous
//
#include <hip/hip_runtime.h>

#define SEQ    2048
#define DMODEL 1024
#define NHEAD  16
#define DHEAD  64
#define NBATCH 2

typedef __bf16 bf16x8 __attribute__((ext_vector_type(8)));
typedef float f32x16 __attribute__((ext_vector_type(16)));
typedef unsigned short ushort8v __attribute__((ext_vector_type(8)));
typedef int int4v __attribute__((ext_vector_type(4)));

static __device__ __forceinline__ unsigned short f2b(float f){
  unsigned int u = __builtin_bit_cast(unsigned int, f);
  u += 0x7fffu + ((u>>16)&1u);            // RNE to bf16
  return (unsigned short)(u>>16);
}
static __device__ __forceinline__ float b2f(unsigned short h){
  unsigned int u = ((unsigned int)h)<<16;
  return __builtin_bit_cast(float, u);
}
static __device__ __forceinline__ unsigned int pk2(float lo, float hi){
  return (unsigned int)f2b(lo) | ((unsigned int)f2b(hi)<<16);
}
static __device__ __forceinline__ f32x16 mfma32(bf16x8 a, bf16x8 b, f32x16 c){
  return __builtin_amdgcn_mfma_f32_32x32x16_bf16(a,b,c,0,0,0);
}

// ---------- A packer: Am[q32][kt][w][lane][8] = bf16(A[k][q]) in mask-consume order ----------
// value at (w = fi*2 + (mm>>1), idx8 = (mm&1)*4 + j) for lane (hi,l31):
//   A[kt*64 + 32*fi + 8*mm + 4*hi + j][q32*32 + l31]
__global__ __launch_bounds__(256) void cvtA(const float* __restrict__ A,
                                            unsigned short* __restrict__ Am){
  const int tid  = threadIdx.x;
  const int lane = tid&63, l31 = lane&31, hi = lane>>5;
  const int q32  = blockIdx.x;                 // 0..63
  const int kt   = blockIdx.y*4 + (tid>>6);    // 0..31
  const int q    = q32*32 + l31;

  unsigned short out8[4][8];
  #pragma unroll
  for (int fi=0; fi<2; fi++){
    #pragma unroll
    for (int mm=0; mm<4; mm++){
      #pragma unroll
      for (int j=0; j<4; j++){
        const int k = kt*64 + 32*fi + 8*mm + 4*hi + j;
        out8[fi*2 + (mm>>1)][(mm&1)*4 + j] = f2b(A[(size_t)k*SEQ + q]);
      }
    }
  }
  unsigned short* dst = Am + ((size_t)(q32*32 + kt)*4)*512 + lane*8;
  #pragma unroll
  for (int w=0; w<4; w++)
    *(ushort8v*)(dst + (size_t)w*512) = *(const ushort8v*)out8[w];
}

// ---------- fused q/k/v projection: Y = (X*W^T + b)*alpha ----------
// z==0: qh row-major [bh][s][dk]
// z==1: Kp packed  [bh][k32][s][lane][8]
// z==2: Vp packed  [bh][k64][s2][dhalf][lane][8]
__global__ __launch_bounds__(256) void proj_qkv(
    const float* __restrict__ qx, const float* __restrict__ kx, const float* __restrict__ vx,
    const float* __restrict__ Wq, const float* __restrict__ Wk, const float* __restrict__ Wv,
    const float* __restrict__ bq, const float* __restrict__ bk, const float* __restrict__ bv,
    unsigned short* __restrict__ qh, unsigned short* __restrict__ Kp, unsigned short* __restrict__ Vp)
{
  const int z = blockIdx.z;
  const float* X    = (z==0)? qx : (z==1)? kx : vx;
  const float* W    = (z==0)? Wq : (z==1)? Wk : Wv;
  const float* bias = (z==0)? bq : (z==1)? bk : bv;
  const float alpha = (z==0)? 0.125f : 1.0f;   // fold 1/sqrt(DK) into qh

  const int mb = blockIdx.y*128, nb = blockIdx.x*128;
  __shared__ unsigned short Xs[128][72];
  __shared__ unsigned short Ws[128][72];
  const int tid = threadIdx.x;
  const int lane = tid&63, wave = tid>>6;
  const int wr = wave>>1, wc = wave&1, l31 = lane&31, hi = lane>>5;
  f32x16 acc[2][2] = {};
  const int sr = tid>>1, sh = (tid&1)*32;

  for (int kb=0; kb<DMODEL; kb+=64){
    const float* xrow = X + (size_t)(mb+sr)*DMODEL + kb + sh;
    const float* wrow = W + (size_t)(nb+sr)*DMODEL + kb + sh;
    #pragma unroll
    for (int c=0;c<4;c++){
      float4 a0 = *(const float4*)(xrow + 8*c);
      float4 a1 = *(const float4*)(xrow + 8*c + 4);
      int4v px; px.x = pk2(a0.x,a0.y); px.y = pk2(a0.z,a0.w);
                px.z = pk2(a1.x,a1.y); px.w = pk2(a1.z,a1.w);
      *(int4v*)&Xs[sr][sh + 8*c] = px;
      float4 b0 = *(const float4*)(wrow + 8*c);
      float4 b1 = *(const float4*)(wrow + 8*c + 4);
      int4v pw; pw.x = pk2(b0.x,b0.y); pw.y = pk2(b0.z,b0.w);
                pw.z = pk2(b1.x,b1.y); pw.w = pk2(b1.z,b1.w);
      *(int4v*)&Ws[sr][sh + 8*c] = pw;
    }
    __syncthreads();
    #pragma unroll
    for (int s=0;s<4;s++){
      bf16x8 a0 = *(const bf16x8*)&Xs[64*wr +      l31][16*s + 8*hi];
      bf16x8 a1 = *(const bf16x8*)&Xs[64*wr + 32 + l31][16*s + 8*hi];
      bf16x8 b0 = *(const bf16x8*)&Ws[64*wc +      l31][16*s + 8*hi];
      bf16x8 b1 = *(const bf16x8*)&Ws[64*wc + 32 + l31][16*s + 8*hi];
      acc[0][0] = mfma32(a0,b0,acc[0][0]);
      acc[0][1] = mfma32(a0,b1,acc[0][1]);
      acc[1][0] = mfma32(a1,b0,acc[1][0]);
      acc[1][1] = mfma32(a1,b1,acc[1][1]);
    }
    __syncthreads();
  }
  #pragma unroll
  for (int fj=0; fj<2; fj++){
    const int e = nb + 64*wc + 32*fj + l31;
    const float bv_ = bias[e];
    const int hh = e>>6, dk = e&63;
    #pragma unroll
    for (int fi=0; fi<2; fi++){
      #pragma unroll
      for (int r=0;r<16;r++){
        const int i = mb + 64*wr + 32*fi + (r&3) + 8*(r>>2) + 4*hi;
        const int bb = i>>11, ss = i&(SEQ-1);
        const int bhh = bb*NHEAD + hh;
        const unsigned short val = f2b((acc[fi][fj][r] + bv_)*alpha);
        if (z==0){
          qh[((size_t)bhh*SEQ + ss)*DHEAD + dk] = val;
        } else if (z==1){
          const size_t addr = (((size_t)(bhh*64 + (ss>>5))*4 + (dk>>4))*64
                               + ((dk>>3)&1)*32 + (ss&31))*8 + (dk&7);
          Kp[addr] = val;
        } else {
          const size_t addr = ((((size_t)(bhh*32 + (ss>>6))*4 + ((ss>>4)&3))*2
                               + (dk>>5))*64 + ((ss>>3)&1)*32 + (dk&31))*8 + (ss&7);
          Vp[addr] = val;
        }
      }
    }
  }
}

// ---------- fused masked attention: x = (Qh Kh^T ∘ A^T) Vh ----------
// All k-loop streams pre-packed in fragment order -> every load = base + lane*16B,
// fully coalesced, L2-resident. No LDS / barriers in the k-loop.
__global__ __launch_bounds__(256,4) void attn(
    const unsigned short* __restrict__ qh, const unsigned short* __restrict__ Kp,
    const unsigned short* __restrict__ Vp, const unsigned short* __restrict__ Am,
    unsigned short* __restrict__ xbuf)
{
  const int qblk = blockIdx.x;     // 0..31  (64 q-rows per block)
  const int bh   = blockIdx.y;     // 0..31
  const int tid  = threadIdx.x;
  const int lane = tid&63, wave = tid>>6;
  const int qsub = wave&1, khalf = wave>>1;
  const int l31 = lane&31, hi = lane>>5;

  const int qrow = qblk*64 + qsub*32 + l31;
  const int q32  = qblk*2 + qsub;
  const unsigned short* qp = qh + ((size_t)bh*SEQ + qrow)*DHEAD;
  bf16x8 Qf[4];
  #pragma unroll
  for (int t=0;t<4;t++) Qf[t] = *(const bf16x8*)(qp + 16*t + 8*hi);

  f32x16 xacc[2] = {};

  const unsigned short* kpb = Kp + ((size_t)bh*64)*2048 + lane*8;   // [k32][s][lane][8]
  const unsigned short* vpb = Vp + ((size_t)bh*32)*4096 + lane*8;   // [k64][s2][dhalf][lane][8]
  const unsigned short* apb = Am + ((size_t)q32*32)*2048 + lane*8;  // [kt][w][lane][8]

  for (int t=0; t<16; t++){
    const int kt = khalf*16 + t;
    // scores^T = K * Q^T (scale pre-folded into qh)
    f32x16 sacc[2] = {};
    const unsigned short* kp0 = kpb + (size_t)(kt*2)*2048;
    #pragma unroll
    for (int s=0;s<4;s++){
      bf16x8 k0 = *(const bf16x8*)(kp0 + (size_t)s*512);
      bf16x8 k1 = *(const bf16x8*)(kp0 + (size_t)(4+s)*512);
      sacc[0] = mfma32(k0, Qf[s], sacc[0]);
      sacc[1] = mfma32(k1, Qf[s], sacc[1]);
    }
    // mask values (packed in consume order)
    const unsigned short* ap = apb + (size_t)kt*2048;
    ushort8v a8[4];
    #pragma unroll
    for (int w=0;w<4;w++) a8[w] = *(const ushort8v*)(ap + (size_t)w*512);
    // mask multiply (P^T[k][q] *= A[k][q]) + pack to bf16 pairs along k
    unsigned int wv[2][4], xv[2][4];
    #pragma unroll
    for (int fi=0; fi<2; fi++){
      #pragma unroll
      for (int mm=0; mm<4; mm++){
        const int w = fi*2 + (mm>>1), b0 = (mm&1)*4;
        const int rb2 = 4*mm;
        float p0 = sacc[fi][rb2+0]*b2f(a8[w][b0+0]);
        float p1 = sacc[fi][rb2+1]*b2f(a8[w][b0+1]);
        float p2 = sacc[fi][rb2+2]*b2f(a8[w][b0+2]);
        float p3 = sacc[fi][rb2+3]*b2f(a8[w][b0+3]);
        wv[fi][mm] = pk2(p0,p1);
        xv[fi][mm] = pk2(p2,p3);
      }
    }
    // x += P * V  (P A-operand assembled in-register; V fragments packed)
    const unsigned short* vp = vpb + (size_t)kt*4096;
    #pragma unroll
    for (int s2=0; s2<4; s2++){
      const int fi = s2>>1, sl = s2&1;
      unsigned int pw = __shfl_xor(hi ? wv[fi][2*sl] : wv[fi][2*sl+1], 32, 64);
      unsigned int px = __shfl_xor(hi ? xv[fi][2*sl] : xv[fi][2*sl+1], 32, 64);
      int4v av;
      av.x = (int)(hi ? pw : wv[fi][2*sl]);
      av.y = (int)(hi ? px : xv[fi][2*sl]);
      av.z = (int)(hi ? wv[fi][2*sl+1] : pw);
      av.w = (int)(hi ? xv[fi][2*sl+1] : px);
      bf16x8 pa = __builtin_bit_cast(bf16x8, av);
      bf16x8 v0 = *(const bf16x8*)(vp + (size_t)(s2*2+0)*512);
      bf16x8 v1 = *(const bf16x8*)(vp + (size_t)(s2*2+1)*512);
      xacc[0] = mfma32(pa, v0, xacc[0]);
      xacc[1] = mfma32(pa, v1, xacc[1]);
    }
  }

  // cross-wave split-K reduction (single barrier)
  __shared__ float Red[2][64][33];
  if (khalf==1){
    #pragma unroll
    for (int j=0;j<2;j++)
      #pragma unroll
      for (int r=0;r<16;r++)
        Red[qsub][lane][16*j+r] = xacc[j][r];
  }
  __syncthreads();
  if (khalf==0){
    #pragma unroll
    for (int j=0;j<2;j++)
      #pragma unroll
      for (int r=0;r<16;r++)
        xacc[j][r] += Red[qsub][lane][16*j+r];
    const int b = bh>>4, h = bh&15;
    #pragma unroll
    for (int fj=0; fj<2; fj++){
      #pragma unroll
      for (int r=0;r<16;r++){
        const int qq = qblk*64 + qsub*32 + (r&3) + 8*(r>>2) + 4*hi;
        const int dd = 32*fj + l31;
        xbuf[((size_t)(b*SEQ + qq))*DMODEL + h*DHEAD + dd] = f2b(xacc[fj][r]);
      }
    }
  }
}

// ---------- output projection: out = x * Wo^T + bo (fp32 out) ----------
__global__ __launch_bounds__(256) void oproj(
    const unsigned short* __restrict__ xb, const float* __restrict__ Wo,
    const float* __restrict__ bo, float* __restrict__ out)
{
  const int mb = blockIdx.y*128, nb = blockIdx.x*128;
  __shared__ unsigned short Xs[128][72];
  __shared__ unsigned short Ws[128][72];
  const int tid = threadIdx.x;
  const int lane = tid&63, wave = tid>>6;
  const int wr = wave>>1, wc = wave&1, l31 = lane&31, hi = lane>>5;
  f32x16 acc[2][2] = {};
  const int sr = tid>>1, sh = (tid&1)*32;
  for (int kb=0; kb<DMODEL; kb+=64){
    const unsigned short* xrow = xb + (size_t)(mb+sr)*DMODEL + kb + sh;
    const float* wrow = Wo + (size_t)(nb+sr)*DMODEL + kb + sh;
    #pragma unroll
    for (int c=0;c<4;c++){
      *(ushort8v*)&Xs[sr][sh + 8*c] = *(const ushort8v*)(xrow + 8*c);
      float4 b0 = *(const float4*)(wrow + 8*c);
      float4 b1 = *(const float4*)(wrow + 8*c + 4);
      int4v pw; pw.x = pk2(b0.x,b0.y); pw.y = pk2(b0.z,b0.w);
                pw.z = pk2(b1.x,b1.y); pw.w = pk2(b1.z,b1.w);
      *(int4v*)&Ws[sr][sh + 8*c] = pw;
    }
    __syncthreads();
    #pragma unroll
    for (int s=0;s<4;s++){
      bf16x8 a0 = *(const bf16x8*)&Xs[64*wr +      l31][16*s + 8*hi];
      bf16x8 a1 = *(const bf16x8*)&Xs[64*wr + 32 + l31][16*s + 8*hi];
      bf16x8 b0 = *(const bf16x8*)&Ws[64*wc +      l31][16*s + 8*hi];
      bf16x8 b1 = *(const bf16x8*)&Ws[64*wc + 32 + l31][16*s + 8*hi];
      acc[0][0] = mfma32(a0,b0,acc[0][0]);
      acc[0][1] = mfma32(a0,b1,acc[0][1]);
      acc[1][0] = mfma32(a1,b0,acc[1][0]);
      acc[1][1] = mfma32(a1,b1,acc[1][1]);
    }
    __syncthreads();
  }
  #pragma unroll
  for (int fj=0; fj<2; fj++){
    const int e = nb + 64*wc + 32*fj + l31;
    const float bv_ = bo[e];
    #pragma unroll
    for (int fi=0; fi<2; fi++){
      #pragma unroll
      for (int r=0;r<16;r++){
        const int i = mb + 64*wr + 32*fi + (r&3) + 8*(r>>2) + 4*hi;
        out[(size_t)i*DMODEL + e] = acc[fi][fj][r] + bv_;
      }
    }
  }
}

extern "C" void kernel_launch(void* const* d_in, const int* in_sizes, int n_in,
                              void* d_out, int out_size, void* d_ws, size_t ws_size,
                              hipStream_t stream)
{
  const float* q  = (const float*)d_in[0];
  const float* k  = (const float*)d_in[1];
  const float* v  = (const float*)d_in[2];
  const float* A  = (const float*)d_in[3];
  const float* Wq = (const float*)d_in[4];
  const float* bq = (const float*)d_in[5];
  const float* Wk = (const float*)d_in[6];
  const float* bk = (const float*)d_in[7];
  const float* Wv = (const float*)d_in[8];
  const float* bv = (const float*)d_in[9];
  const float* Wo = (const float*)d_in[10];
  const float* bo = (const float*)d_in[11];
  float* out = (float*)d_out;

  // workspace layout (bf16 elements): qh, Kp, Vp, x, Am  -> 5 * 8MB = 40MB
  unsigned short* ws = (unsigned short*)d_ws;
  const size_t NE = (size_t)NBATCH*SEQ*DMODEL;   // 4M elements
  unsigned short* qh = ws;
  unsigned short* Kp = qh + NE;
  unsigned short* Vp = Kp + NE;
  unsigned short* xb = Vp + NE;
  unsigned short* Am = xb + NE;

  cvtA<<<dim3(64, 8), 256, 0, stream>>>(A, Am);
  proj_qkv<<<dim3(DMODEL/128, (NBATCH*SEQ)/128, 3), 256, 0, stream>>>(
      q,k,v, Wq,Wk,Wv, bq,bk,bv, qh,Kp,Vp);
  attn<<<dim3(SEQ/64, NBATCH*NHEAD), 256, 0, stream>>>(qh, Kp, Vp, Am, xb);
  oproj<<<dim3(DMODEL/128, (NBATCH*SEQ)/128), 256, 0, stream>>>(xb, Wo, bo, out);
}

// Round 4
// 225.912 us; speedup vs baseline: 1.5677x; 1.1049x over previous
//
#include <hip/hip_runtime.h>

#define SEQ    2048
#define DMODEL 1024
#define NHEAD  16
#define DHEAD  64
#define NBATCH 2

typedef __bf16 bf16x8 __attribute__((ext_vector_type(8)));
typedef float f32x16 __attribute__((ext_vector_type(16)));
typedef unsigned short ushort8v __attribute__((ext_vector_type(8)));
typedef int int4v __attribute__((ext_vector_type(4)));

static __device__ __forceinline__ unsigned short f2b(float f){
  unsigned int u = __builtin_bit_cast(unsigned int, f);
  u += 0x7fffu + ((u>>16)&1u);            // RNE to bf16
  return (unsigned short)(u>>16);
}
static __device__ __forceinline__ float b2f(unsigned short h){
  unsigned int u = ((unsigned int)h)<<16;
  return __builtin_bit_cast(float, u);
}
static __device__ __forceinline__ unsigned int pk2(float lo, float hi){
  return (unsigned int)f2b(lo) | ((unsigned int)f2b(hi)<<16);
}
static __device__ __forceinline__ f32x16 mfma32(bf16x8 a, bf16x8 b, f32x16 c){
  return __builtin_amdgcn_mfma_f32_32x32x16_bf16(a,b,c,0,0,0);
}
#define GLOAD16(g,l) __builtin_amdgcn_global_load_lds( \
    (const __attribute__((address_space(1))) void*)(g), \
    (__attribute__((address_space(3))) void*)(l), 16, 0, 0)

// ---------- bulk fp32 -> bf16 conversion of q,k,v ----------
__global__ __launch_bounds__(256) void cvtX(
    const float* __restrict__ q, const float* __restrict__ k, const float* __restrict__ v,
    unsigned short* __restrict__ xq, unsigned short* __restrict__ xk, unsigned short* __restrict__ xv)
{
  const int z = blockIdx.z;
  const float* s = (z==0)? q : (z==1)? k : v;
  unsigned short* d = (z==0)? xq : (z==1)? xk : xv;
  const int n8 = NBATCH*SEQ*DMODEL/8;
  for (int i = blockIdx.x*256 + threadIdx.x; i < n8; i += gridDim.x*256){
    float4 f0 = ((const float4*)s)[2*i];
    float4 f1 = ((const float4*)s)[2*i+1];
    int4v p; p.x = pk2(f0.x,f0.y); p.y = pk2(f0.z,f0.w);
             p.z = pk2(f1.x,f1.y); p.w = pk2(f1.z,f1.w);
    ((int4v*)d)[i] = p;
  }
}

// ---------- A packer: Am[q32][kt][w][lane][8] = bf16(A[k][q]) in mask-consume order ----------
__global__ __launch_bounds__(256) void cvtA(const float* __restrict__ A,
                                            unsigned short* __restrict__ Am){
  const int tid  = threadIdx.x;
  const int lane = tid&63, l31 = lane&31, hi = lane>>5;
  const int q32  = blockIdx.x;                 // 0..63
  const int kt   = blockIdx.y*4 + (tid>>6);    // 0..31
  const int q    = q32*32 + l31;

  unsigned short out8[4][8];
  #pragma unroll
  for (int fi=0; fi<2; fi++){
    #pragma unroll
    for (int mm=0; mm<4; mm++){
      #pragma unroll
      for (int j=0; j<4; j++){
        const int k = kt*64 + 32*fi + 8*mm + 4*hi + j;
        out8[fi*2 + (mm>>1)][(mm&1)*4 + j] = f2b(A[(size_t)k*SEQ + q]);
      }
    }
  }
  unsigned short* dst = Am + ((size_t)(q32*32 + kt)*4)*512 + lane*8;
  #pragma unroll
  for (int w=0; w<4; w++)
    *(ushort8v*)(dst + (size_t)w*512) = *(const ushort8v*)out8[w];
}

// ---------- fused q/k/v projection: Y = (X*W^T + b)*alpha ----------
// X pre-converted bf16 (gload_lds staging); W fp32 converted in-kernel (L2-resident).
// z==0: qh row-major; z==1: Kp packed; z==2: Vp packed.
__global__ __launch_bounds__(256) void proj_qkv(
    const unsigned short* __restrict__ Xq, const unsigned short* __restrict__ Xk, const unsigned short* __restrict__ Xv,
    const float* __restrict__ Wq, const float* __restrict__ Wk, const float* __restrict__ Wv,
    const float* __restrict__ bq, const float* __restrict__ bk, const float* __restrict__ bv,
    unsigned short* __restrict__ qh, unsigned short* __restrict__ Kp, unsigned short* __restrict__ Vp)
{
  const int z = blockIdx.z;
  const unsigned short* X = (z==0)? Xq : (z==1)? Xk : Xv;
  const float* W    = (z==0)? Wq : (z==1)? Wk : Wv;
  const float* bias = (z==0)? bq : (z==1)? bk : bv;
  const float alpha = (z==0)? 0.125f : 1.0f;   // fold 1/sqrt(DK) into qh

  const int mb = blockIdx.y*128, nb = blockIdx.x*128;
  __shared__ unsigned short As[128*64];     // linear (gload_lds dest)
  __shared__ unsigned short Ws[128][72];
  const int tid = threadIdx.x;
  const int lane = tid&63, wave = tid>>6;
  const int wr = wave>>1, wc = wave&1, l31 = lane&31, hi = lane>>5;
  f32x16 acc[2][2] = {};
  const int sr = tid>>1, sh = (tid&1)*32;

  const unsigned short* gA = X + (size_t)(mb + wave*32 + (lane>>3))*DMODEL + (lane&7)*8;
  unsigned short* lA = As + wave*2048;      // wave-uniform LDS base

  for (int kb=0; kb<DMODEL; kb+=64){
    #pragma unroll
    for (int i=0;i<4;i++)
      GLOAD16(gA + (size_t)i*8*DMODEL + kb, lA + i*512);
    const float* wrow = W + (size_t)(nb+sr)*DMODEL + kb + sh;
    #pragma unroll
    for (int c=0;c<4;c++){
      float4 b0 = *(const float4*)(wrow + 8*c);
      float4 b1 = *(const float4*)(wrow + 8*c + 4);
      int4v pw; pw.x = pk2(b0.x,b0.y); pw.y = pk2(b0.z,b0.w);
                pw.z = pk2(b1.x,b1.y); pw.w = pk2(b1.z,b1.w);
      *(int4v*)&Ws[sr][sh + 8*c] = pw;
    }
    __syncthreads();
    #pragma unroll
    for (int s=0;s<4;s++){
      bf16x8 a0 = *(const bf16x8*)(As + (size_t)(64*wr +      l31)*64 + 16*s + 8*hi);
      bf16x8 a1 = *(const bf16x8*)(As + (size_t)(64*wr + 32 + l31)*64 + 16*s + 8*hi);
      bf16x8 b0 = *(const bf16x8*)&Ws[64*wc +      l31][16*s + 8*hi];
      bf16x8 b1 = *(const bf16x8*)&Ws[64*wc + 32 + l31][16*s + 8*hi];
      acc[0][0] = mfma32(a0,b0,acc[0][0]);
      acc[0][1] = mfma32(a0,b1,acc[0][1]);
      acc[1][0] = mfma32(a1,b0,acc[1][0]);
      acc[1][1] = mfma32(a1,b1,acc[1][1]);
    }
    __syncthreads();
  }
  #pragma unroll
  for (int fj=0; fj<2; fj++){
    const int e = nb + 64*wc + 32*fj + l31;
    const float bv_ = bias[e];
    const int hh = e>>6, dk = e&63;
    #pragma unroll
    for (int fi=0; fi<2; fi++){
      #pragma unroll
      for (int r=0;r<16;r++){
        const int i = mb + 64*wr + 32*fi + (r&3) + 8*(r>>2) + 4*hi;
        const int bb = i>>11, ss = i&(SEQ-1);
        const int bhh = bb*NHEAD + hh;
        const unsigned short val = f2b((acc[fi][fj][r] + bv_)*alpha);
        if (z==0){
          qh[((size_t)bhh*SEQ + ss)*DHEAD + dk] = val;
        } else if (z==1){
          const size_t addr = (((size_t)(bhh*64 + (ss>>5))*4 + (dk>>4))*64
                               + ((dk>>3)&1)*32 + (ss&31))*8 + (dk&7);
          Kp[addr] = val;
        } else {
          const size_t addr = ((((size_t)(bhh*32 + (ss>>6))*4 + ((ss>>4)&3))*2
                               + (dk>>5))*64 + ((ss>>3)&1)*32 + (dk&31))*8 + (ss&7);
          Vp[addr] = val;
        }
      }
    }
  }
}

// ---------- fused masked attention: x = (Qh Kh^T ∘ A^T) Vh ----------
__global__ __launch_bounds__(256,4) void attn(
    const unsigned short* __restrict__ qh, const unsigned short* __restrict__ Kp,
    const unsigned short* __restrict__ Vp, const unsigned short* __restrict__ Am,
    unsigned short* __restrict__ xbuf)
{
  const int qblk = blockIdx.x;     // 0..31  (64 q-rows per block)
  const int bh   = blockIdx.y;     // 0..31
  const int tid  = threadIdx.x;
  const int lane = tid&63, wave = tid>>6;
  const int qsub = wave&1, khalf = wave>>1;
  const int l31 = lane&31, hi = lane>>5;

  const int qrow = qblk*64 + qsub*32 + l31;
  const int q32  = qblk*2 + qsub;
  const unsigned short* qp = qh + ((size_t)bh*SEQ + qrow)*DHEAD;
  bf16x8 Qf[4];
  #pragma unroll
  for (int t=0;t<4;t++) Qf[t] = *(const bf16x8*)(qp + 16*t + 8*hi);

  f32x16 xacc[2] = {};

  const unsigned short* kpb = Kp + ((size_t)bh*64)*2048 + lane*8;   // [k32][s][lane][8]
  const unsigned short* vpb = Vp + ((size_t)bh*32)*4096 + lane*8;   // [k64][s2][dhalf][lane][8]
  const unsigned short* apb = Am + ((size_t)q32*32)*2048 + lane*8;  // [kt][w][lane][8]

  for (int t=0; t<16; t++){
    const int kt = khalf*16 + t;
    // scores^T = K * Q^T (scale pre-folded into qh)
    f32x16 sacc[2] = {};
    const unsigned short* kp0 = kpb + (size_t)(kt*2)*2048;
    #pragma unroll
    for (int s=0;s<4;s++){
      bf16x8 k0 = *(const bf16x8*)(kp0 + (size_t)s*512);
      bf16x8 k1 = *(const bf16x8*)(kp0 + (size_t)(4+s)*512);
      sacc[0] = mfma32(k0, Qf[s], sacc[0]);
      sacc[1] = mfma32(k1, Qf[s], sacc[1]);
    }
    // mask values (packed in consume order)
    const unsigned short* ap = apb + (size_t)kt*2048;
    ushort8v a8[4];
    #pragma unroll
    for (int w=0;w<4;w++) a8[w] = *(const ushort8v*)(ap + (size_t)w*512);
    // mask multiply (P^T[k][q] *= A[k][q]) + pack to bf16 pairs along k
    unsigned int wv[2][4], xv[2][4];
    #pragma unroll
    for (int fi=0; fi<2; fi++){
      #pragma unroll
      for (int mm=0; mm<4; mm++){
        const int w = fi*2 + (mm>>1), b0 = (mm&1)*4;
        const int rb2 = 4*mm;
        float p0 = sacc[fi][rb2+0]*b2f(a8[w][b0+0]);
        float p1 = sacc[fi][rb2+1]*b2f(a8[w][b0+1]);
        float p2 = sacc[fi][rb2+2]*b2f(a8[w][b0+2]);
        float p3 = sacc[fi][rb2+3]*b2f(a8[w][b0+3]);
        wv[fi][mm] = pk2(p0,p1);
        xv[fi][mm] = pk2(p2,p3);
      }
    }
    // x += P * V  (P A-operand assembled in-register; V fragments packed)
    const unsigned short* vp = vpb + (size_t)kt*4096;
    #pragma unroll
    for (int s2=0; s2<4; s2++){
      const int fi = s2>>1, sl = s2&1;
      unsigned int pw = __shfl_xor(hi ? wv[fi][2*sl] : wv[fi][2*sl+1], 32, 64);
      unsigned int px = __shfl_xor(hi ? xv[fi][2*sl] : xv[fi][2*sl+1], 32, 64);
      int4v av;
      av.x = (int)(hi ? pw : wv[fi][2*sl]);
      av.y = (int)(hi ? px : xv[fi][2*sl]);
      av.z = (int)(hi ? wv[fi][2*sl+1] : pw);
      av.w = (int)(hi ? xv[fi][2*sl+1] : px);
      bf16x8 pa = __builtin_bit_cast(bf16x8, av);
      bf16x8 v0 = *(const bf16x8*)(vp + (size_t)(s2*2+0)*512);
      bf16x8 v1 = *(const bf16x8*)(vp + (size_t)(s2*2+1)*512);
      xacc[0] = mfma32(pa, v0, xacc[0]);
      xacc[1] = mfma32(pa, v1, xacc[1]);
    }
  }

  // cross-wave split-K reduction (single barrier)
  __shared__ float Red[2][64][33];
  if (khalf==1){
    #pragma unroll
    for (int j=0;j<2;j++)
      #pragma unroll
      for (int r=0;r<16;r++)
        Red[qsub][lane][16*j+r] = xacc[j][r];
  }
  __syncthreads();
  if (khalf==0){
    #pragma unroll
    for (int j=0;j<2;j++)
      #pragma unroll
      for (int r=0;r<16;r++)
        xacc[j][r] += Red[qsub][lane][16*j+r];
    const int b = bh>>4, h = bh&15;
    #pragma unroll
    for (int fj=0; fj<2; fj++){
      #pragma unroll
      for (int r=0;r<16;r++){
        const int qq = qblk*64 + qsub*32 + (r&3) + 8*(r>>2) + 4*hi;
        const int dd = 32*fj + l31;
        xbuf[((size_t)(b*SEQ + qq))*DMODEL + h*DHEAD + dd] = f2b(xacc[fj][r]);
      }
    }
  }
}

// ---------- output projection: out = x * Wo^T + bo (fp32 out) ----------
__global__ __launch_bounds__(256) void oproj(
    const unsigned short* __restrict__ xb, const float* __restrict__ Wo,
    const float* __restrict__ bo, float* __restrict__ out)
{
  const int mb = blockIdx.y*128, nb = blockIdx.x*128;
  __shared__ unsigned short As[128*64];
  __shared__ unsigned short Ws[128][72];
  const int tid = threadIdx.x;
  const int lane = tid&63, wave = tid>>6;
  const int wr = wave>>1, wc = wave&1, l31 = lane&31, hi = lane>>5;
  f32x16 acc[2][2] = {};
  const int sr = tid>>1, sh = (tid&1)*32;

  const unsigned short* gA = xb + (size_t)(mb + wave*32 + (lane>>3))*DMODEL + (lane&7)*8;
  unsigned short* lA = As + wave*2048;

  for (int kb=0; kb<DMODEL; kb+=64){
    #pragma unroll
    for (int i=0;i<4;i++)
      GLOAD16(gA + (size_t)i*8*DMODEL + kb, lA + i*512);
    const float* wrow = Wo + (size_t)(nb+sr)*DMODEL + kb + sh;
    #pragma unroll
    for (int c=0;c<4;c++){
      float4 b0 = *(const float4*)(wrow + 8*c);
      float4 b1 = *(const float4*)(wrow + 8*c + 4);
      int4v pw; pw.x = pk2(b0.x,b0.y); pw.y = pk2(b0.z,b0.w);
                pw.z = pk2(b1.x,b1.y); pw.w = pk2(b1.z,b1.w);
      *(int4v*)&Ws[sr][sh + 8*c] = pw;
    }
    __syncthreads();
    #pragma unroll
    for (int s=0;s<4;s++){
      bf16x8 a0 = *(const bf16x8*)(As + (size_t)(64*wr +      l31)*64 + 16*s + 8*hi);
      bf16x8 a1 = *(const bf16x8*)(As + (size_t)(64*wr + 32 + l31)*64 + 16*s + 8*hi);
      bf16x8 b0 = *(const bf16x8*)&Ws[64*wc +      l31][16*s + 8*hi];
      bf16x8 b1 = *(const bf16x8*)&Ws[64*wc + 32 + l31][16*s + 8*hi];
      acc[0][0] = mfma32(a0,b0,acc[0][0]);
      acc[0][1] = mfma32(a0,b1,acc[0][1]);
      acc[1][0] = mfma32(a1,b0,acc[1][0]);
      acc[1][1] = mfma32(a1,b1,acc[1][1]);
    }
    __syncthreads();
  }
  #pragma unroll
  for (int fj=0; fj<2; fj++){
    const int e = nb + 64*wc + 32*fj + l31;
    const float bv_ = bo[e];
    #pragma unroll
    for (int fi=0; fi<2; fi++){
      #pragma unroll
      for (int r=0;r<16;r++){
        const int i = mb + 64*wr + 32*fi + (r&3) + 8*(r>>2) + 4*hi;
        out[(size_t)i*DMODEL + e] = acc[fi][fj][r] + bv_;
      }
    }
  }
}

extern "C" void kernel_launch(void* const* d_in, const int* in_sizes, int n_in,
                              void* d_out, int out_size, void* d_ws, size_t ws_size,
                              hipStream_t stream)
{
  const float* q  = (const float*)d_in[0];
  const float* k  = (const float*)d_in[1];
  const float* v  = (const float*)d_in[2];
  const float* A  = (const float*)d_in[3];
  const float* Wq = (const float*)d_in[4];
  const float* bq = (const float*)d_in[5];
  const float* Wk = (const float*)d_in[6];
  const float* bk = (const float*)d_in[7];
  const float* Wv = (const float*)d_in[8];
  const float* bv = (const float*)d_in[9];
  const float* Wo = (const float*)d_in[10];
  const float* bo = (const float*)d_in[11];
  float* out = (float*)d_out;

  // ws layout (bf16 elems): qh, Kp, Vp, xb(=Xvb scratch), Am  -> 40MB
  // d_out doubles as scratch for Xqb/Xkb (dead before oproj writes it).
  unsigned short* ws = (unsigned short*)d_ws;
  const size_t NE = (size_t)NBATCH*SEQ*DMODEL;   // 4M elements
  unsigned short* qh  = ws;
  unsigned short* Kp  = qh + NE;
  unsigned short* Vp  = Kp + NE;
  unsigned short* xb  = Vp + NE;                 // also Xvb before attn
  unsigned short* Am  = xb + NE;
  unsigned short* Xqb = (unsigned short*)d_out;  // [0, 8MB)
  unsigned short* Xkb = Xqb + NE;                // [8MB, 16MB)
  unsigned short* Xvb = xb;

  cvtA<<<dim3(64, 8), 256, 0, stream>>>(A, Am);
  cvtX<<<dim3(1024, 1, 3), 256, 0, stream>>>(q, k, v, Xqb, Xkb, Xvb);
  proj_qkv<<<dim3(DMODEL/128, (NBATCH*SEQ)/128, 3), 256, 0, stream>>>(
      Xqb, Xkb, Xvb, Wq, Wk, Wv, bq, bk, bv, qh, Kp, Vp);
  attn<<<dim3(SEQ/64, NBATCH*NHEAD), 256, 0, stream>>>(qh, Kp, Vp, Am, xb);
  oproj<<<dim3(DMODEL/128, (NBATCH*SEQ)/128), 256, 0, stream>>>(xb, Wo, bo, out);
}

// Round 5
// 162.991 us; speedup vs baseline: 2.1729x; 1.3860x over previous
//
#include <hip/hip_runtime.h>

#define SEQ    2048
#define DMODEL 1024
#define NHEAD  16
#define DHEAD  64
#define NBATCH 2

typedef __bf16 bf16x8 __attribute__((ext_vector_type(8)));
typedef float f32x16 __attribute__((ext_vector_type(16)));
typedef unsigned short ushort8v __attribute__((ext_vector_type(8)));
typedef int int4v __attribute__((ext_vector_type(4)));

static __device__ __forceinline__ unsigned short f2b(float f){
  unsigned int u = __builtin_bit_cast(unsigned int, f);
  u += 0x7fffu + ((u>>16)&1u);            // RNE to bf16
  return (unsigned short)(u>>16);
}
static __device__ __forceinline__ float b2f(unsigned short h){
  unsigned int u = ((unsigned int)h)<<16;
  return __builtin_bit_cast(float, u);
}
static __device__ __forceinline__ unsigned int pk2(float lo, float hi){
  return (unsigned int)f2b(lo) | ((unsigned int)f2b(hi)<<16);
}
static __device__ __forceinline__ f32x16 mfma32(bf16x8 a, bf16x8 b, f32x16 c){
  return __builtin_amdgcn_mfma_f32_32x32x16_bf16(a,b,c,0,0,0);
}
static __device__ __forceinline__ ushort8v cvt8(const float* p){
  float4 f0 = *(const float4*)p;
  float4 f1 = *(const float4*)(p+4);
  ushort8v r;
  r[0]=f2b(f0.x); r[1]=f2b(f0.y); r[2]=f2b(f0.z); r[3]=f2b(f0.w);
  r[4]=f2b(f1.x); r[5]=f2b(f1.y); r[6]=f2b(f1.z); r[7]=f2b(f1.w);
  return r;
}

// ---------- pack X (q,k,v) fp32 -> bf16 MFMA-A-fragment order ----------
// Xp[g][s][lane][8] = X[g*32 + (lane&31)][16*s + 8*(lane>>5) + j]
__global__ __launch_bounds__(256) void cvtXpack(
    const float* __restrict__ q, const float* __restrict__ k, const float* __restrict__ v,
    unsigned short* __restrict__ Xq, unsigned short* __restrict__ Xk, unsigned short* __restrict__ Xv)
{
  const int z = blockIdx.z;
  const float* S = (z==0)? q : (z==1)? k : v;
  unsigned short* D = (z==0)? Xq : (z==1)? Xk : Xv;
  const int g = blockIdx.x;                       // 0..127
  const int wave = threadIdx.x>>6, lane = threadIdx.x&63;
  const int l31 = lane&31, hi = lane>>5;
  const float* src = S + (size_t)(g*32 + l31)*DMODEL + 8*hi + 256*wave;
  unsigned short* dst = D + (size_t)(g*64 + wave*16)*512 + lane*8;
  #pragma unroll
  for (int i=0;i<16;i++)
    *(ushort8v*)(dst + (size_t)i*512) = cvt8(src + 16*i);
}

// ---------- pack Wq,Wk,Wv,Wo fp32 -> bf16 MFMA-B-fragment order ----------
// Wp[z][n32][s][lane][8] = W[n32*32 + (lane&31)][16*s + 8*(lane>>5) + j]
__global__ __launch_bounds__(256) void cvtWpack(
    const float* __restrict__ Wq, const float* __restrict__ Wk,
    const float* __restrict__ Wv, const float* __restrict__ Wo,
    unsigned short* __restrict__ Wp)
{
  const int z = blockIdx.z;
  const float* S = (z==0)? Wq : (z==1)? Wk : (z==2)? Wv : Wo;
  const int g = blockIdx.x;                       // 0..31
  const int wave = threadIdx.x>>6, lane = threadIdx.x&63;
  const int l31 = lane&31, hi = lane>>5;
  const float* src = S + (size_t)(g*32 + l31)*DMODEL + 8*hi + 256*wave;
  unsigned short* dst = Wp + (size_t)((z*32 + g)*64 + wave*16)*512 + lane*8;
  #pragma unroll
  for (int i=0;i<16;i++)
    *(ushort8v*)(dst + (size_t)i*512) = cvt8(src + 16*i);
}

// ---------- A packer: Am[q32][kt][w][lane][8] = bf16(A[k][q]) in mask-consume order ----------
__global__ __launch_bounds__(256) void cvtA(const float* __restrict__ A,
                                            unsigned short* __restrict__ Am){
  const int tid  = threadIdx.x;
  const int lane = tid&63, l31 = lane&31, hi = lane>>5;
  const int q32  = blockIdx.x;                 // 0..63
  const int kt   = blockIdx.y*4 + (tid>>6);    // 0..31
  const int q    = q32*32 + l31;

  unsigned short out8[4][8];
  #pragma unroll
  for (int fi=0; fi<2; fi++){
    #pragma unroll
    for (int mm=0; mm<4; mm++){
      #pragma unroll
      for (int j=0; j<4; j++){
        const int k = kt*64 + 32*fi + 8*mm + 4*hi + j;
        out8[fi*2 + (mm>>1)][(mm&1)*4 + j] = f2b(A[(size_t)k*SEQ + q]);
      }
    }
  }
  unsigned short* dst = Am + ((size_t)(q32*32 + kt)*4)*512 + lane*8;
  #pragma unroll
  for (int w=0; w<4; w++)
    *(ushort8v*)(dst + (size_t)w*512) = *(const ushort8v*)out8[w];
}

// ---------- fused q/k/v projection: LDS-free, barrier-free fragment GEMM ----------
// z==0: qh row-major; z==1: Kp packed; z==2: Vp packed.
__global__ __launch_bounds__(256,3) void proj_qkv(
    const unsigned short* __restrict__ Xq, const unsigned short* __restrict__ Xk, const unsigned short* __restrict__ Xv,
    const unsigned short* __restrict__ Wp,
    const float* __restrict__ bq, const float* __restrict__ bk, const float* __restrict__ bv,
    unsigned short* __restrict__ qh, unsigned short* __restrict__ Kp, unsigned short* __restrict__ Vp)
{
  const int z = blockIdx.z;
  const unsigned short* X = (z==0)? Xq : (z==1)? Xk : Xv;
  const unsigned short* W = Wp + (size_t)z*1048576;
  const float* bias = (z==0)? bq : (z==1)? bk : bv;
  const float alpha = (z==0)? 0.125f : 1.0f;   // fold 1/sqrt(DK) into qh

  // XCD-chunked swizzle within this z-slice: 256 blocks -> 8 chunks of 32
  const int orig = blockIdx.y*8 + blockIdx.x;
  const int virt = (orig&7)*32 + (orig>>3);
  const int bx = virt&7, by = virt>>3;
  const int mb = by*128, nb = bx*128;

  const int tid = threadIdx.x;
  const int lane = tid&63, wave = tid>>6;
  const int wr = wave>>1, wc = wave&1, l31 = lane&31, hi = lane>>5;
  f32x16 acc[2][2] = {};

  const unsigned short* a0p = X + (size_t)((mb>>5) + 2*wr    )*32768 + lane*8;
  const unsigned short* a1p = a0p + 32768;
  const unsigned short* b0p = W + (size_t)((nb>>5) + 2*wc    )*32768 + lane*8;
  const unsigned short* b1p = b0p + 32768;

  #pragma unroll 4
  for (int s=0;s<64;s++){
    bf16x8 a0 = *(const bf16x8*)(a0p + (size_t)s*512);
    bf16x8 a1 = *(const bf16x8*)(a1p + (size_t)s*512);
    bf16x8 b0 = *(const bf16x8*)(b0p + (size_t)s*512);
    bf16x8 b1 = *(const bf16x8*)(b1p + (size_t)s*512);
    acc[0][0] = mfma32(a0,b0,acc[0][0]);
    acc[0][1] = mfma32(a0,b1,acc[0][1]);
    acc[1][0] = mfma32(a1,b0,acc[1][0]);
    acc[1][1] = mfma32(a1,b1,acc[1][1]);
  }

  #pragma unroll
  for (int fj=0; fj<2; fj++){
    const int e = nb + 64*wc + 32*fj + l31;
    const float bv_ = bias[e];
    const int hh = e>>6, dk = e&63;
    #pragma unroll
    for (int fi=0; fi<2; fi++){
      #pragma unroll
      for (int r=0;r<16;r++){
        const int i = mb + 64*wr + 32*fi + (r&3) + 8*(r>>2) + 4*hi;
        const int bb = i>>11, ss = i&(SEQ-1);
        const int bhh = bb*NHEAD + hh;
        const unsigned short val = f2b((acc[fi][fj][r] + bv_)*alpha);
        if (z==0){
          qh[((size_t)bhh*SEQ + ss)*DHEAD + dk] = val;
        } else if (z==1){
          const size_t addr = (((size_t)(bhh*64 + (ss>>5))*4 + (dk>>4))*64
                               + ((dk>>3)&1)*32 + (ss&31))*8 + (dk&7);
          Kp[addr] = val;
        } else {
          const size_t addr = ((((size_t)(bhh*32 + (ss>>6))*4 + ((ss>>4)&3))*2
                               + (dk>>5))*64 + ((ss>>3)&1)*32 + (dk&31))*8 + (ss&7);
          Vp[addr] = val;
        }
      }
    }
  }
}

// ---------- fused masked attention: x = (Qh Kh^T ∘ A^T) Vh ----------
// epilogue writes x in packed MFMA-A-fragment order for oproj
__global__ __launch_bounds__(256,4) void attn(
    const unsigned short* __restrict__ qh, const unsigned short* __restrict__ Kp,
    const unsigned short* __restrict__ Vp, const unsigned short* __restrict__ Am,
    unsigned short* __restrict__ xp)
{
  const int qblk = blockIdx.x;     // 0..31  (64 q-rows per block)
  const int bh   = blockIdx.y;     // 0..31
  const int tid  = threadIdx.x;
  const int lane = tid&63, wave = tid>>6;
  const int qsub = wave&1, khalf = wave>>1;
  const int l31 = lane&31, hi = lane>>5;

  const int qrow = qblk*64 + qsub*32 + l31;
  const int q32  = qblk*2 + qsub;
  const unsigned short* qp = qh + ((size_t)bh*SEQ + qrow)*DHEAD;
  bf16x8 Qf[4];
  #pragma unroll
  for (int t=0;t<4;t++) Qf[t] = *(const bf16x8*)(qp + 16*t + 8*hi);

  f32x16 xacc[2] = {};

  const unsigned short* kpb = Kp + ((size_t)bh*64)*2048 + lane*8;   // [k32][s][lane][8]
  const unsigned short* vpb = Vp + ((size_t)bh*32)*4096 + lane*8;   // [k64][s2][dhalf][lane][8]
  const unsigned short* apb = Am + ((size_t)q32*32)*2048 + lane*8;  // [kt][w][lane][8]

  for (int t=0; t<16; t++){
    const int kt = khalf*16 + t;
    // scores^T = K * Q^T (scale pre-folded into qh)
    f32x16 sacc[2] = {};
    const unsigned short* kp0 = kpb + (size_t)(kt*2)*2048;
    #pragma unroll
    for (int s=0;s<4;s++){
      bf16x8 k0 = *(const bf16x8*)(kp0 + (size_t)s*512);
      bf16x8 k1 = *(const bf16x8*)(kp0 + (size_t)(4+s)*512);
      sacc[0] = mfma32(k0, Qf[s], sacc[0]);
      sacc[1] = mfma32(k1, Qf[s], sacc[1]);
    }
    // mask values (packed in consume order)
    const unsigned short* ap = apb + (size_t)kt*2048;
    ushort8v a8[4];
    #pragma unroll
    for (int w=0;w<4;w++) a8[w] = *(const ushort8v*)(ap + (size_t)w*512);
    // mask multiply (P^T[k][q] *= A[k][q]) + pack to bf16 pairs along k
    unsigned int wv[2][4], xv[2][4];
    #pragma unroll
    for (int fi=0; fi<2; fi++){
      #pragma unroll
      for (int mm=0; mm<4; mm++){
        const int w = fi*2 + (mm>>1), b0 = (mm&1)*4;
        const int rb2 = 4*mm;
        float p0 = sacc[fi][rb2+0]*b2f(a8[w][b0+0]);
        float p1 = sacc[fi][rb2+1]*b2f(a8[w][b0+1]);
        float p2 = sacc[fi][rb2+2]*b2f(a8[w][b0+2]);
        float p3 = sacc[fi][rb2+3]*b2f(a8[w][b0+3]);
        wv[fi][mm] = pk2(p0,p1);
        xv[fi][mm] = pk2(p2,p3);
      }
    }
    // x += P * V  (P A-operand assembled in-register; V fragments packed)
    const unsigned short* vp = vpb + (size_t)kt*4096;
    #pragma unroll
    for (int s2=0; s2<4; s2++){
      const int fi = s2>>1, sl = s2&1;
      unsigned int pw = __shfl_xor(hi ? wv[fi][2*sl] : wv[fi][2*sl+1], 32, 64);
      unsigned int px = __shfl_xor(hi ? xv[fi][2*sl] : xv[fi][2*sl+1], 32, 64);
      int4v av;
      av.x = (int)(hi ? pw : wv[fi][2*sl]);
      av.y = (int)(hi ? px : xv[fi][2*sl]);
      av.z = (int)(hi ? wv[fi][2*sl+1] : pw);
      av.w = (int)(hi ? xv[fi][2*sl+1] : px);
      bf16x8 pa = __builtin_bit_cast(bf16x8, av);
      bf16x8 v0 = *(const bf16x8*)(vp + (size_t)(s2*2+0)*512);
      bf16x8 v1 = *(const bf16x8*)(vp + (size_t)(s2*2+1)*512);
      xacc[0] = mfma32(pa, v0, xacc[0]);
      xacc[1] = mfma32(pa, v1, xacc[1]);
    }
  }

  // cross-wave split-K reduction (single barrier)
  __shared__ float Red[2][64][33];
  if (khalf==1){
    #pragma unroll
    for (int j=0;j<2;j++)
      #pragma unroll
      for (int r=0;r<16;r++)
        Red[qsub][lane][16*j+r] = xacc[j][r];
  }
  __syncthreads();
  if (khalf==0){
    #pragma unroll
    for (int j=0;j<2;j++)
      #pragma unroll
      for (int r=0;r<16;r++)
        xacc[j][r] += Red[qsub][lane][16*j+r];
    const int b = bh>>4, h = bh&15;
    #pragma unroll
    for (int fj=0; fj<2; fj++){
      const int scol = h*4 + fj*2 + (l31>>4);        // (col>>4)
      const int lpart = ((l31>>3)&1)*32;
      const int epart = l31&7;
      #pragma unroll
      for (int r=0;r<16;r++){
        const int qq = qblk*64 + qsub*32 + (r&3) + 8*(r>>2) + 4*hi;
        const int row = b*SEQ + qq;
        const size_t addr = ((size_t)(row>>5)*64 + scol)*512 + (lpart + (row&31))*8 + epart;
        xp[addr] = f2b(xacc[fj][r]);
      }
    }
  }
}

// ---------- output projection: LDS-free fragment GEMM, fp32 out ----------
__global__ __launch_bounds__(256,4) void oproj(
    const unsigned short* __restrict__ Xp, const unsigned short* __restrict__ Wop,
    const float* __restrict__ bo, float* __restrict__ out)
{
  // grid (16, 32): BN=64, BM=128. XCD-chunked swizzle over 512 blocks.
  const int orig = blockIdx.y*16 + blockIdx.x;
  const int virt = (orig&7)*64 + (orig>>3);
  const int bx = virt&15, by = virt>>4;
  const int mb = by*128, nb = bx*64;

  const int tid = threadIdx.x;
  const int lane = tid&63, wave = tid>>6;       // wave = m-subgroup (32 rows)
  const int l31 = lane&31, hi = lane>>5;
  f32x16 acc[2] = {};

  const unsigned short* ap  = Xp  + (size_t)((mb>>5) + wave)*32768 + lane*8;
  const unsigned short* b0p = Wop + (size_t)(nb>>5)*32768 + lane*8;
  const unsigned short* b1p = b0p + 32768;

  #pragma unroll 4
  for (int s=0;s<64;s++){
    bf16x8 a  = *(const bf16x8*)(ap  + (size_t)s*512);
    bf16x8 b0 = *(const bf16x8*)(b0p + (size_t)s*512);
    bf16x8 b1 = *(const bf16x8*)(b1p + (size_t)s*512);
    acc[0] = mfma32(a,b0,acc[0]);
    acc[1] = mfma32(a,b1,acc[1]);
  }

  #pragma unroll
  for (int fj=0; fj<2; fj++){
    const int e = nb + 32*fj + l31;
    const float bv_ = bo[e];
    #pragma unroll
    for (int r=0;r<16;r++){
      const int i = mb + 32*wave + (r&3) + 8*(r>>2) + 4*hi;
      out[(size_t)i*DMODEL + e] = acc[fj][r] + bv_;
    }
  }
}

extern "C" void kernel_launch(void* const* d_in, const int* in_sizes, int n_in,
                              void* d_out, int out_size, void* d_ws, size_t ws_size,
                              hipStream_t stream)
{
  const float* q  = (const float*)d_in[0];
  const float* k  = (const float*)d_in[1];
  const float* v  = (const float*)d_in[2];
  const float* A  = (const float*)d_in[3];
  const float* Wq = (const float*)d_in[4];
  const float* bq = (const float*)d_in[5];
  const float* Wk = (const float*)d_in[6];
  const float* bk = (const float*)d_in[7];
  const float* Wv = (const float*)d_in[8];
  const float* bv = (const float*)d_in[9];
  const float* Wo = (const float*)d_in[10];
  const float* bo = (const float*)d_in[11];
  float* out = (float*)d_out;

  // ws (bf16 elems): qh, Kp, Vp, xb, Wp  -> 40MB. d_out doubles as scratch:
  //   phase1: Xqp [0,8MB), Xkp [8,16MB)   (consumed by proj)
  //   phase2: Am  [0,8MB)                 (written by cvtA after proj, read by attn)
  //   phase3: out fp32 16MB               (oproj, final)
  unsigned short* ws = (unsigned short*)d_ws;
  const size_t NE = (size_t)NBATCH*SEQ*DMODEL;   // 4M elements
  unsigned short* qh  = ws;
  unsigned short* Kp  = qh + NE;
  unsigned short* Vp  = Kp + NE;
  unsigned short* xb  = Vp + NE;                 // Xvp before attn, packed-x after
  unsigned short* Wp  = xb + NE;                 // 4 packed weight matrices
  unsigned short* Xqp = (unsigned short*)d_out;
  unsigned short* Xkp = Xqp + NE;
  unsigned short* Am  = (unsigned short*)d_out;
  unsigned short* Xvp = xb;

  cvtXpack<<<dim3(128, 1, 3), 256, 0, stream>>>(q, k, v, Xqp, Xkp, Xvp);
  cvtWpack<<<dim3(32, 1, 4), 256, 0, stream>>>(Wq, Wk, Wv, Wo, Wp);
  proj_qkv<<<dim3(8, 32, 3), 256, 0, stream>>>(
      Xqp, Xkp, Xvp, Wp, bq, bk, bv, qh, Kp, Vp);
  cvtA<<<dim3(64, 8), 256, 0, stream>>>(A, Am);
  attn<<<dim3(SEQ/64, NBATCH*NHEAD), 256, 0, stream>>>(qh, Kp, Vp, Am, xb);
  oproj<<<dim3(16, 32), 256, 0, stream>>>(xb, Wp + (size_t)3*1048576, bo, out);
}

// Round 6
// 162.367 us; speedup vs baseline: 2.1812x; 1.0038x over previous
//
#include <hip/hip_runtime.h>

#define SEQ    2048
#define DMODEL 1024
#define NHEAD  16
#define DHEAD  64
#define NBATCH 2

typedef __bf16 bf16x8 __attribute__((ext_vector_type(8)));
typedef float f32x16 __attribute__((ext_vector_type(16)));
typedef float f32x8 __attribute__((ext_vector_type(8)));
typedef unsigned short ushort8v __attribute__((ext_vector_type(8)));
typedef unsigned int uint2v __attribute__((ext_vector_type(2)));
typedef int int4v __attribute__((ext_vector_type(4)));

static __device__ __forceinline__ unsigned short f2b(float f){
  unsigned int u = __builtin_bit_cast(unsigned int, f);
  u += 0x7fffu + ((u>>16)&1u);            // RNE to bf16
  return (unsigned short)(u>>16);
}
static __device__ __forceinline__ unsigned int pk2(float lo, float hi){
  return (unsigned int)f2b(lo) | ((unsigned int)f2b(hi)<<16);
}
static __device__ __forceinline__ f32x16 mfma32(bf16x8 a, bf16x8 b, f32x16 c){
  return __builtin_amdgcn_mfma_f32_32x32x16_bf16(a,b,c,0,0,0);
}
static __device__ __forceinline__ ushort8v cvt8(const float* p){
  float4 f0 = *(const float4*)p;
  float4 f1 = *(const float4*)(p+4);
  ushort8v r;
  r[0]=f2b(f0.x); r[1]=f2b(f0.y); r[2]=f2b(f0.z); r[3]=f2b(f0.w);
  r[4]=f2b(f1.x); r[5]=f2b(f1.y); r[6]=f2b(f1.z); r[7]=f2b(f1.w);
  return r;
}

// ---------- pack X (q,k,v) fp32 -> bf16 MFMA-A-fragment order ----------
// Xp[g][s][lane][8] = X[g*32 + (lane&31)][16*s + 8*(lane>>5) + j]
__global__ __launch_bounds__(256) void cvtXpack(
    const float* __restrict__ q, const float* __restrict__ k, const float* __restrict__ v,
    unsigned short* __restrict__ Xq, unsigned short* __restrict__ Xk, unsigned short* __restrict__ Xv)
{
  const int z = blockIdx.z;
  const float* S = (z==0)? q : (z==1)? k : v;
  unsigned short* D = (z==0)? Xq : (z==1)? Xk : Xv;
  const int g = blockIdx.x;                       // 0..127
  const int wave = threadIdx.x>>6, lane = threadIdx.x&63;
  const int l31 = lane&31, hi = lane>>5;
  const float* src = S + (size_t)(g*32 + l31)*DMODEL + 8*hi + 256*wave;
  unsigned short* dst = D + (size_t)(g*64 + wave*16)*512 + lane*8;
  #pragma unroll
  for (int i=0;i<16;i++)
    *(ushort8v*)(dst + (size_t)i*512) = cvt8(src + 16*i);
}

// ---------- pack Wq,Wk,Wv,Wo fp32 -> bf16 MFMA-B-fragment order ----------
__global__ __launch_bounds__(256) void cvtWpack(
    const float* __restrict__ Wq, const float* __restrict__ Wk,
    const float* __restrict__ Wv, const float* __restrict__ Wo,
    unsigned short* __restrict__ Wp)
{
  const int z = blockIdx.z;
  const float* S = (z==0)? Wq : (z==1)? Wk : (z==2)? Wv : Wo;
  const int g = blockIdx.x;                       // 0..31
  const int wave = threadIdx.x>>6, lane = threadIdx.x&63;
  const int l31 = lane&31, hi = lane>>5;
  const float* src = S + (size_t)(g*32 + l31)*DMODEL + 8*hi + 256*wave;
  unsigned short* dst = Wp + (size_t)((z*32 + g)*64 + wave*16)*512 + lane*8;
  #pragma unroll
  for (int i=0;i<16;i++)
    *(ushort8v*)(dst + (size_t)i*512) = cvt8(src + 16*i);
}

// ---------- A packer (fp32, no conversion): Amf[q32][kt][w][lane][8] = A[k][q] ----------
// value at (w = fi*2 + (mm>>1), idx8 = (mm&1)*4 + j) for lane (hi,l31):
//   A[kt*64 + 32*fi + 8*mm + 4*hi + j][q32*32 + l31]
__global__ __launch_bounds__(256) void cvtA(const float* __restrict__ A,
                                            float* __restrict__ Amf){
  const int tid  = threadIdx.x;
  const int lane = tid&63, l31 = lane&31, hi = lane>>5;
  const int q32  = blockIdx.x;                 // 0..63
  const int kt   = blockIdx.y*4 + (tid>>6);    // 0..31
  const int q    = q32*32 + l31;

  float out8[4][8];
  #pragma unroll
  for (int fi=0; fi<2; fi++){
    #pragma unroll
    for (int mm=0; mm<4; mm++){
      #pragma unroll
      for (int j=0; j<4; j++){
        const int k = kt*64 + 32*fi + 8*mm + 4*hi + j;
        out8[fi*2 + (mm>>1)][(mm&1)*4 + j] = A[(size_t)k*SEQ + q];
      }
    }
  }
  float* dst = Amf + ((size_t)(q32*32 + kt)*4)*512 + lane*8;
  #pragma unroll
  for (int w=0; w<4; w++)
    *(f32x8*)(dst + (size_t)w*512) = *(const f32x8*)out8[w];
}

// ---------- fused q/k/v projection: LDS-free, barrier-free fragment GEMM ----------
__global__ __launch_bounds__(256,3) void proj_qkv(
    const unsigned short* __restrict__ Xq, const unsigned short* __restrict__ Xk, const unsigned short* __restrict__ Xv,
    const unsigned short* __restrict__ Wp,
    const float* __restrict__ bq, const float* __restrict__ bk, const float* __restrict__ bv,
    unsigned short* __restrict__ qh, unsigned short* __restrict__ Kp, unsigned short* __restrict__ Vp)
{
  const int z = blockIdx.z;
  const unsigned short* X = (z==0)? Xq : (z==1)? Xk : Xv;
  const unsigned short* W = Wp + (size_t)z*1048576;
  const float* bias = (z==0)? bq : (z==1)? bk : bv;
  const float alpha = (z==0)? 0.125f : 1.0f;   // fold 1/sqrt(DK) into qh

  const int orig = blockIdx.y*8 + blockIdx.x;
  const int virt = (orig&7)*32 + (orig>>3);
  const int bx = virt&7, by = virt>>3;
  const int mb = by*128, nb = bx*128;

  const int tid = threadIdx.x;
  const int lane = tid&63, wave = tid>>6;
  const int wr = wave>>1, wc = wave&1, l31 = lane&31, hi = lane>>5;
  f32x16 acc[2][2] = {};

  const unsigned short* a0p = X + (size_t)((mb>>5) + 2*wr)*32768 + lane*8;
  const unsigned short* a1p = a0p + 32768;
  const unsigned short* b0p = W + (size_t)((nb>>5) + 2*wc)*32768 + lane*8;
  const unsigned short* b1p = b0p + 32768;

  #pragma unroll 4
  for (int s=0;s<64;s++){
    bf16x8 a0 = *(const bf16x8*)(a0p + (size_t)s*512);
    bf16x8 a1 = *(const bf16x8*)(a1p + (size_t)s*512);
    bf16x8 b0 = *(const bf16x8*)(b0p + (size_t)s*512);
    bf16x8 b1 = *(const bf16x8*)(b1p + (size_t)s*512);
    acc[0][0] = mfma32(a0,b0,acc[0][0]);
    acc[0][1] = mfma32(a0,b1,acc[0][1]);
    acc[1][0] = mfma32(a1,b0,acc[1][0]);
    acc[1][1] = mfma32(a1,b1,acc[1][1]);
  }

  #pragma unroll
  for (int fj=0; fj<2; fj++){
    const int e = nb + 64*wc + 32*fj + l31;
    const float bv_ = bias[e];
    const int hh = e>>6, dk = e&63;
    #pragma unroll
    for (int fi=0; fi<2; fi++){
      #pragma unroll
      for (int r=0;r<16;r++){
        const int i = mb + 64*wr + 32*fi + (r&3) + 8*(r>>2) + 4*hi;
        const int bb = i>>11, ss = i&(SEQ-1);
        const int bhh = bb*NHEAD + hh;
        const unsigned short val = f2b((acc[fi][fj][r] + bv_)*alpha);
        if (z==0){
          qh[((size_t)bhh*SEQ + ss)*DHEAD + dk] = val;
        } else if (z==1){
          const size_t addr = (((size_t)(bhh*64 + (ss>>5))*4 + (dk>>4))*64
                               + ((dk>>3)&1)*32 + (ss&31))*8 + (dk&7);
          Kp[addr] = val;
        } else {
          const size_t addr = ((((size_t)(bhh*32 + (ss>>6))*4 + ((ss>>4)&3))*2
                               + (dk>>5))*64 + ((ss>>3)&1)*32 + (dk&31))*8 + (ss&7);
          Vp[addr] = val;
        }
      }
    }
  }
}

// ---------- fused masked attention: x = (Qh Kh^T ∘ A^T) Vh ----------
// fp32 mask (no unpack), v_cvt_pk_bf16_f32 pack, permlane32_swap fragment exchange
__global__ __launch_bounds__(256,4) void attn(
    const unsigned short* __restrict__ qh, const unsigned short* __restrict__ Kp,
    const unsigned short* __restrict__ Vp, const float* __restrict__ Amf,
    unsigned short* __restrict__ xp)
{
  const int qblk = blockIdx.x;     // 0..31  (64 q-rows per block)
  const int bh   = blockIdx.y;     // 0..31
  const int tid  = threadIdx.x;
  const int lane = tid&63, wave = tid>>6;
  const int qsub = wave&1, khalf = wave>>1;
  const int l31 = lane&31, hi = lane>>5;

  const int qrow = qblk*64 + qsub*32 + l31;
  const int q32  = qblk*2 + qsub;
  const unsigned short* qp = qh + ((size_t)bh*SEQ + qrow)*DHEAD;
  bf16x8 Qf[4];
  #pragma unroll
  for (int t=0;t<4;t++) Qf[t] = *(const bf16x8*)(qp + 16*t + 8*hi);

  f32x16 xacc[2] = {};

  const unsigned short* kpb = Kp + ((size_t)bh*64)*2048 + lane*8;   // [k32][s][lane][8]
  const unsigned short* vpb = Vp + ((size_t)bh*32)*4096 + lane*8;   // [k64][s2][dhalf][lane][8]
  const float* apbf = Amf + ((size_t)q32*32)*2048 + lane*8;         // [kt][w][lane][8] fp32

  for (int t=0; t<16; t++){
    const int kt = khalf*16 + t;
    const unsigned short* kp0 = kpb + (size_t)(kt*2)*2048;
    const float* apf = apbf + (size_t)kt*2048;
    unsigned int wv[2][4], xv[2][4];
    // per 32-k half: QK^T (scale pre-folded into qh) -> mask -> pack
    #pragma unroll
    for (int fi=0; fi<2; fi++){
      f32x16 sacc = {};
      #pragma unroll
      for (int s=0;s<4;s++){
        bf16x8 kf = *(const bf16x8*)(kp0 + (size_t)(fi*4+s)*512);
        sacc = mfma32(kf, Qf[s], sacc);
      }
      f32x8 af0 = *(const f32x8*)(apf + (size_t)(fi*2+0)*512);
      f32x8 af1 = *(const f32x8*)(apf + (size_t)(fi*2+1)*512);
      #pragma unroll
      for (int mm=0; mm<4; mm++){
        const int b0 = (mm&1)*4, rb2 = 4*mm;
        float a0 = (mm>>1)? af1[b0+0] : af0[b0+0];
        float a1 = (mm>>1)? af1[b0+1] : af0[b0+1];
        float a2 = (mm>>1)? af1[b0+2] : af0[b0+2];
        float a3 = (mm>>1)? af1[b0+3] : af0[b0+3];
        float p0 = sacc[rb2+0]*a0;
        float p1 = sacc[rb2+1]*a1;
        float p2 = sacc[rb2+2]*a2;
        float p3 = sacc[rb2+3]*a3;
        asm("v_cvt_pk_bf16_f32 %0, %1, %2" : "=v"(wv[fi][mm]) : "v"(p0), "v"(p1));
        asm("v_cvt_pk_bf16_f32 %0, %1, %2" : "=v"(xv[fi][mm]) : "v"(p2), "v"(p3));
      }
    }
    // x += P * V  (fragment halves exchanged via permlane32_swap)
    const unsigned short* vp = vpb + (size_t)kt*4096;
    #pragma unroll
    for (int s2=0; s2<4; s2++){
      const int fi = s2>>1, sl = s2&1;
      uint2v rw = __builtin_amdgcn_permlane32_swap(wv[fi][2*sl], wv[fi][2*sl+1], false, false);
      uint2v rx = __builtin_amdgcn_permlane32_swap(xv[fi][2*sl], xv[fi][2*sl+1], false, false);
      int4v av; av.x = (int)rw[0]; av.y = (int)rx[0]; av.z = (int)rw[1]; av.w = (int)rx[1];
      bf16x8 pa = __builtin_bit_cast(bf16x8, av);
      bf16x8 v0 = *(const bf16x8*)(vp + (size_t)(s2*2+0)*512);
      bf16x8 v1 = *(const bf16x8*)(vp + (size_t)(s2*2+1)*512);
      xacc[0] = mfma32(pa, v0, xacc[0]);
      xacc[1] = mfma32(pa, v1, xacc[1]);
    }
  }

  // cross-wave split-K reduction (single barrier)
  __shared__ float Red[2][64][33];
  if (khalf==1){
    #pragma unroll
    for (int j=0;j<2;j++)
      #pragma unroll
      for (int r=0;r<16;r++)
        Red[qsub][lane][16*j+r] = xacc[j][r];
  }
  __syncthreads();
  if (khalf==0){
    #pragma unroll
    for (int j=0;j<2;j++)
      #pragma unroll
      for (int r=0;r<16;r++)
        xacc[j][r] += Red[qsub][lane][16*j+r];
    const int b = bh>>4, h = bh&15;
    #pragma unroll
    for (int fj=0; fj<2; fj++){
      const int scol = h*4 + fj*2 + (l31>>4);
      const int lpart = ((l31>>3)&1)*32;
      const int epart = l31&7;
      #pragma unroll
      for (int r=0;r<16;r++){
        const int qq = qblk*64 + qsub*32 + (r&3) + 8*(r>>2) + 4*hi;
        const int row = b*SEQ + qq;
        const size_t addr = ((size_t)(row>>5)*64 + scol)*512 + (lpart + (row&31))*8 + epart;
        xp[addr] = f2b(xacc[fj][r]);
      }
    }
  }
}

// ---------- output projection: LDS-free fragment GEMM, fp32 out ----------
__global__ __launch_bounds__(256,4) void oproj(
    const unsigned short* __restrict__ Xp, const unsigned short* __restrict__ Wop,
    const float* __restrict__ bo, float* __restrict__ out)
{
  const int orig = blockIdx.y*16 + blockIdx.x;
  const int virt = (orig&7)*64 + (orig>>3);
  const int bx = virt&15, by = virt>>4;
  const int mb = by*128, nb = bx*64;

  const int tid = threadIdx.x;
  const int lane = tid&63, wave = tid>>6;
  const int l31 = lane&31, hi = lane>>5;
  f32x16 acc[2] = {};

  const unsigned short* ap  = Xp  + (size_t)((mb>>5) + wave)*32768 + lane*8;
  const unsigned short* b0p = Wop + (size_t)(nb>>5)*32768 + lane*8;
  const unsigned short* b1p = b0p + 32768;

  #pragma unroll 4
  for (int s=0;s<64;s++){
    bf16x8 a  = *(const bf16x8*)(ap  + (size_t)s*512);
    bf16x8 b0 = *(const bf16x8*)(b0p + (size_t)s*512);
    bf16x8 b1 = *(const bf16x8*)(b1p + (size_t)s*512);
    acc[0] = mfma32(a,b0,acc[0]);
    acc[1] = mfma32(a,b1,acc[1]);
  }

  #pragma unroll
  for (int fj=0; fj<2; fj++){
    const int e = nb + 32*fj + l31;
    const float bv_ = bo[e];
    #pragma unroll
    for (int r=0;r<16;r++){
      const int i = mb + 32*wave + (r&3) + 8*(r>>2) + 4*hi;
      out[(size_t)i*DMODEL + e] = acc[fj][r] + bv_;
    }
  }
}

extern "C" void kernel_launch(void* const* d_in, const int* in_sizes, int n_in,
                              void* d_out, int out_size, void* d_ws, size_t ws_size,
                              hipStream_t stream)
{
  const float* q  = (const float*)d_in[0];
  const float* k  = (const float*)d_in[1];
  const float* v  = (const float*)d_in[2];
  const float* A  = (const float*)d_in[3];
  const float* Wq = (const float*)d_in[4];
  const float* bq = (const float*)d_in[5];
  const float* Wk = (const float*)d_in[6];
  const float* bk = (const float*)d_in[7];
  const float* Wv = (const float*)d_in[8];
  const float* bv = (const float*)d_in[9];
  const float* Wo = (const float*)d_in[10];
  const float* bo = (const float*)d_in[11];
  float* out = (float*)d_out;

  // ws (bf16 elems): qh, Kp, Vp, xb, Wp -> 40MB. d_out as scratch:
  //   phase1: Xqp [0,8MB), Xkp [8,16MB)   (consumed by proj)
  //   phase2: Amf fp32 [0,16MB)           (written by cvtA after proj, read by attn)
  //   phase3: final fp32 out              (oproj)
  unsigned short* ws = (unsigned short*)d_ws;
  const size_t NE = (size_t)NBATCH*SEQ*DMODEL;   // 4M elements
  unsigned short* qh  = ws;
  unsigned short* Kp  = qh + NE;
  unsigned short* Vp  = Kp + NE;
  unsigned short* xb  = Vp + NE;                 // Xvp before attn, packed-x after
  unsigned short* Wp  = xb + NE;                 // 4 packed weight matrices
  unsigned short* Xqp = (unsigned short*)d_out;
  unsigned short* Xkp = Xqp + NE;
  float*          Amf = (float*)d_out;           // 2048*2048 fp32 = exact d_out size
  unsigned short* Xvp = xb;

  cvtXpack<<<dim3(128, 1, 3), 256, 0, stream>>>(q, k, v, Xqp, Xkp, Xvp);
  cvtWpack<<<dim3(32, 1, 4), 256, 0, stream>>>(Wq, Wk, Wv, Wo, Wp);
  proj_qkv<<<dim3(8, 32, 3), 256, 0, stream>>>(
      Xqp, Xkp, Xvp, Wp, bq, bk, bv, qh, Kp, Vp);
  cvtA<<<dim3(64, 8), 256, 0, stream>>>(A, Amf);
  attn<<<dim3(SEQ/64, NBATCH*NHEAD), 256, 0, stream>>>(qh, Kp, Vp, Amf, xb);
  oproj<<<dim3(16, 32), 256, 0, stream>>>(xb, Wp + (size_t)3*1048576, bo, out);
}

// Round 7
// 156.015 us; speedup vs baseline: 2.2700x; 1.0407x over previous
//
#include <hip/hip_runtime.h>

#define SEQ    2048
#define DMODEL 1024
#define NHEAD  16
#define DHEAD  64
#define NBATCH 2

typedef __bf16 bf16x8 __attribute__((ext_vector_type(8)));
typedef float f32x16 __attribute__((ext_vector_type(16)));
typedef float f32x8 __attribute__((ext_vector_type(8)));
typedef unsigned short ushort8v __attribute__((ext_vector_type(8)));
typedef unsigned int uint2v __attribute__((ext_vector_type(2)));
typedef int int4v __attribute__((ext_vector_type(4)));

static __device__ __forceinline__ unsigned short f2b(float f){
  unsigned int u = __builtin_bit_cast(unsigned int, f);
  u += 0x7fffu + ((u>>16)&1u);            // RNE to bf16
  return (unsigned short)(u>>16);
}
static __device__ __forceinline__ float b2f(unsigned short h){
  unsigned int u = ((unsigned int)h)<<16;
  return __builtin_bit_cast(float, u);
}
static __device__ __forceinline__ f32x16 mfma32(bf16x8 a, bf16x8 b, f32x16 c){
  return __builtin_amdgcn_mfma_f32_32x32x16_bf16(a,b,c,0,0,0);
}
static __device__ __forceinline__ ushort8v cvt8(const float* p){
  float4 f0 = *(const float4*)p;
  float4 f1 = *(const float4*)(p+4);
  ushort8v r;
  r[0]=f2b(f0.x); r[1]=f2b(f0.y); r[2]=f2b(f0.z); r[3]=f2b(f0.w);
  r[4]=f2b(f1.x); r[5]=f2b(f1.y); r[6]=f2b(f1.z); r[7]=f2b(f1.w);
  return r;
}

// ---------- pack X (q,k,v) fp32 -> bf16 MFMA-A-fragment order ----------
// Xp[g][s][lane][8] = X[g*32 + (lane&31)][16*s + 8*(lane>>5) + j]
__global__ __launch_bounds__(256) void cvtXpack(
    const float* __restrict__ q, const float* __restrict__ k, const float* __restrict__ v,
    unsigned short* __restrict__ Xq, unsigned short* __restrict__ Xk, unsigned short* __restrict__ Xv)
{
  const int z = blockIdx.z;
  const float* S = (z==0)? q : (z==1)? k : v;
  unsigned short* D = (z==0)? Xq : (z==1)? Xk : Xv;
  const int g = blockIdx.x;                       // 0..127
  const int wave = threadIdx.x>>6, lane = threadIdx.x&63;
  const int l31 = lane&31, hi = lane>>5;
  const float* src = S + (size_t)(g*32 + l31)*DMODEL + 8*hi + 256*wave;
  unsigned short* dst = D + (size_t)(g*64 + wave*16)*512 + lane*8;
  #pragma unroll
  for (int i=0;i<16;i++)
    *(ushort8v*)(dst + (size_t)i*512) = cvt8(src + 16*i);
}

// ---------- pack Wq,Wk,Wv,Wo fp32 -> bf16 MFMA-B-fragment order ----------
__global__ __launch_bounds__(256) void cvtWpack(
    const float* __restrict__ Wq, const float* __restrict__ Wk,
    const float* __restrict__ Wv, const float* __restrict__ Wo,
    unsigned short* __restrict__ Wp)
{
  const int z = blockIdx.z;
  const float* S = (z==0)? Wq : (z==1)? Wk : (z==2)? Wv : Wo;
  const int g = blockIdx.x;                       // 0..31
  const int wave = threadIdx.x>>6, lane = threadIdx.x&63;
  const int l31 = lane&31, hi = lane>>5;
  const float* src = S + (size_t)(g*32 + l31)*DMODEL + 8*hi + 256*wave;
  unsigned short* dst = Wp + (size_t)((z*32 + g)*64 + wave*16)*512 + lane*8;
  #pragma unroll
  for (int i=0;i<16;i++)
    *(ushort8v*)(dst + (size_t)i*512) = cvt8(src + 16*i);
}

// ---------- A packer (bf16): Am[q32][kt][w][lane][8] = bf16(A[k][q]) ----------
// value at (w = fi*2 + (mm>>1), idx8 = (mm&1)*4 + j) for lane (hi,l31):
//   A[kt*64 + 32*fi + 8*mm + 4*hi + j][q32*32 + l31]
__global__ __launch_bounds__(256) void cvtA(const float* __restrict__ A,
                                            unsigned short* __restrict__ Am){
  const int tid  = threadIdx.x;
  const int lane = tid&63, l31 = lane&31, hi = lane>>5;
  const int q32  = blockIdx.x;                 // 0..63
  const int kt   = blockIdx.y*4 + (tid>>6);    // 0..31
  const int q    = q32*32 + l31;

  unsigned short out8[4][8];
  #pragma unroll
  for (int fi=0; fi<2; fi++){
    #pragma unroll
    for (int mm=0; mm<4; mm++){
      #pragma unroll
      for (int j=0; j<4; j++){
        const int k = kt*64 + 32*fi + 8*mm + 4*hi + j;
        out8[fi*2 + (mm>>1)][(mm&1)*4 + j] = f2b(A[(size_t)k*SEQ + q]);
      }
    }
  }
  unsigned short* dst = Am + ((size_t)(q32*32 + kt)*4)*512 + lane*8;
  #pragma unroll
  for (int w=0; w<4; w++)
    *(ushort8v*)(dst + (size_t)w*512) = *(const ushort8v*)out8[w];
}

// ---------- fused q/k/v projection: LDS-free, barrier-free fragment GEMM ----------
__global__ __launch_bounds__(256,3) void proj_qkv(
    const unsigned short* __restrict__ Xq, const unsigned short* __restrict__ Xk, const unsigned short* __restrict__ Xv,
    const unsigned short* __restrict__ Wp,
    const float* __restrict__ bq, const float* __restrict__ bk, const float* __restrict__ bv,
    unsigned short* __restrict__ qh, unsigned short* __restrict__ Kp, unsigned short* __restrict__ Vp)
{
  const int z = blockIdx.z;
  const unsigned short* X = (z==0)? Xq : (z==1)? Xk : Xv;
  const unsigned short* W = Wp + (size_t)z*1048576;
  const float* bias = (z==0)? bq : (z==1)? bk : bv;
  const float alpha = (z==0)? 0.125f : 1.0f;   // fold 1/sqrt(DK) into qh

  const int orig = blockIdx.y*8 + blockIdx.x;
  const int virt = (orig&7)*32 + (orig>>3);
  const int bx = virt&7, by = virt>>3;
  const int mb = by*128, nb = bx*128;

  const int tid = threadIdx.x;
  const int lane = tid&63, wave = tid>>6;
  const int wr = wave>>1, wc = wave&1, l31 = lane&31, hi = lane>>5;
  f32x16 acc[2][2] = {};

  const unsigned short* a0p = X + (size_t)((mb>>5) + 2*wr)*32768 + lane*8;
  const unsigned short* a1p = a0p + 32768;
  const unsigned short* b0p = W + (size_t)((nb>>5) + 2*wc)*32768 + lane*8;
  const unsigned short* b1p = b0p + 32768;

  #pragma unroll 4
  for (int s=0;s<64;s++){
    bf16x8 a0 = *(const bf16x8*)(a0p + (size_t)s*512);
    bf16x8 a1 = *(const bf16x8*)(a1p + (size_t)s*512);
    bf16x8 b0 = *(const bf16x8*)(b0p + (size_t)s*512);
    bf16x8 b1 = *(const bf16x8*)(b1p + (size_t)s*512);
    acc[0][0] = mfma32(a0,b0,acc[0][0]);
    acc[0][1] = mfma32(a0,b1,acc[0][1]);
    acc[1][0] = mfma32(a1,b0,acc[1][0]);
    acc[1][1] = mfma32(a1,b1,acc[1][1]);
  }

  #pragma unroll
  for (int fj=0; fj<2; fj++){
    const int e = nb + 64*wc + 32*fj + l31;
    const float bv_ = bias[e];
    const int hh = e>>6, dk = e&63;
    #pragma unroll
    for (int fi=0; fi<2; fi++){
      #pragma unroll
      for (int r=0;r<16;r++){
        const int i = mb + 64*wr + 32*fi + (r&3) + 8*(r>>2) + 4*hi;
        const int bb = i>>11, ss = i&(SEQ-1);
        const int bhh = bb*NHEAD + hh;
        const unsigned short val = f2b((acc[fi][fj][r] + bv_)*alpha);
        if (z==0){
          qh[((size_t)bhh*SEQ + ss)*DHEAD + dk] = val;
        } else if (z==1){
          const size_t addr = (((size_t)(bhh*64 + (ss>>5))*4 + (dk>>4))*64
                               + ((dk>>3)&1)*32 + (ss&31))*8 + (dk&7);
          Kp[addr] = val;
        } else {
          const size_t addr = ((((size_t)(bhh*32 + (ss>>6))*4 + ((ss>>4)&3))*2
                               + (dk>>5))*64 + ((ss>>3)&1)*32 + (dk&31))*8 + (ss&7);
          Vp[addr] = val;
        }
      }
    }
  }
}

// ---------- fused masked attention: x = (Qh Kh^T ∘ A^T) Vh ----------
// 512 threads = 8 waves = 4 q32-subtiles x 2 khalves; 128 q-rows per block.
// bf16 mask; XCD-clustered bh mapping so each XCD's K/V slice (~4MB) stays L2-resident.
__global__ __launch_bounds__(512,4) void attn(
    const unsigned short* __restrict__ qh, const unsigned short* __restrict__ Kp,
    const unsigned short* __restrict__ Vp, const unsigned short* __restrict__ Am,
    unsigned short* __restrict__ xp)
{
  // 512 blocks total: xcd = orig&7 owns bh in [xcd*4, xcd*4+4)
  const int orig = blockIdx.y*16 + blockIdx.x;
  const int xcd = orig&7, within = orig>>3;
  const int bh   = xcd*4 + (within>>4);   // 0..31
  const int qblk = within&15;             // 0..15 (128 q-rows each)

  const int tid  = threadIdx.x;
  const int lane = tid&63, wave = tid>>6;
  const int qsub = wave&3, khalf = wave>>2;
  const int l31 = lane&31, hi = lane>>5;

  const int q32  = qblk*4 + qsub;
  const int qrow = q32*32 + l31;
  const unsigned short* qp = qh + ((size_t)bh*SEQ + qrow)*DHEAD;
  bf16x8 Qf[4];
  #pragma unroll
  for (int t=0;t<4;t++) Qf[t] = *(const bf16x8*)(qp + 16*t + 8*hi);

  f32x16 xacc[2] = {};

  const unsigned short* kpb = Kp + ((size_t)bh*64)*2048 + lane*8;   // [k32][s][lane][8]
  const unsigned short* vpb = Vp + ((size_t)bh*32)*4096 + lane*8;   // [k64][s2][dhalf][lane][8]
  const unsigned short* apb = Am + ((size_t)q32*32)*2048 + lane*8;  // [kt][w][lane][8] bf16

  for (int t=0; t<16; t++){
    const int kt = khalf*16 + t;
    const unsigned short* kp0 = kpb + (size_t)(kt*2)*2048;
    const unsigned short* ap  = apb + (size_t)kt*2048;
    unsigned int wv[2][4], xv[2][4];
    // per 32-k half: QK^T (scale pre-folded into qh) -> mask -> pack
    #pragma unroll
    for (int fi=0; fi<2; fi++){
      f32x16 sacc = {};
      #pragma unroll
      for (int s=0;s<4;s++){
        bf16x8 kf = *(const bf16x8*)(kp0 + (size_t)(fi*4+s)*512);
        sacc = mfma32(kf, Qf[s], sacc);
      }
      ushort8v a80 = *(const ushort8v*)(ap + (size_t)(fi*2+0)*512);
      ushort8v a81 = *(const ushort8v*)(ap + (size_t)(fi*2+1)*512);
      #pragma unroll
      for (int mm=0; mm<4; mm++){
        const int b0 = (mm&1)*4, rb2 = 4*mm;
        float p0 = sacc[rb2+0]*((mm>>1)? b2f(a81[b0+0]) : b2f(a80[b0+0]));
        float p1 = sacc[rb2+1]*((mm>>1)? b2f(a81[b0+1]) : b2f(a80[b0+1]));
        float p2 = sacc[rb2+2]*((mm>>1)? b2f(a81[b0+2]) : b2f(a80[b0+2]));
        float p3 = sacc[rb2+3]*((mm>>1)? b2f(a81[b0+3]) : b2f(a80[b0+3]));
        asm("v_cvt_pk_bf16_f32 %0, %1, %2" : "=v"(wv[fi][mm]) : "v"(p0), "v"(p1));
        asm("v_cvt_pk_bf16_f32 %0, %1, %2" : "=v"(xv[fi][mm]) : "v"(p2), "v"(p3));
      }
    }
    // x += P * V  (fragment halves exchanged via permlane32_swap)
    const unsigned short* vp = vpb + (size_t)kt*4096;
    __builtin_amdgcn_s_setprio(1);
    #pragma unroll
    for (int s2=0; s2<4; s2++){
      const int fi = s2>>1, sl = s2&1;
      uint2v rw = __builtin_amdgcn_permlane32_swap(wv[fi][2*sl], wv[fi][2*sl+1], false, false);
      uint2v rx = __builtin_amdgcn_permlane32_swap(xv[fi][2*sl], xv[fi][2*sl+1], false, false);
      int4v av; av.x = (int)rw[0]; av.y = (int)rx[0]; av.z = (int)rw[1]; av.w = (int)rx[1];
      bf16x8 pa = __builtin_bit_cast(bf16x8, av);
      bf16x8 v0 = *(const bf16x8*)(vp + (size_t)(s2*2+0)*512);
      bf16x8 v1 = *(const bf16x8*)(vp + (size_t)(s2*2+1)*512);
      xacc[0] = mfma32(pa, v0, xacc[0]);
      xacc[1] = mfma32(pa, v1, xacc[1]);
    }
    __builtin_amdgcn_s_setprio(0);
  }

  // cross-wave split-K reduction (single barrier)
  __shared__ float Red[4][64][33];
  if (khalf==1){
    #pragma unroll
    for (int j=0;j<2;j++)
      #pragma unroll
      for (int r=0;r<16;r++)
        Red[qsub][lane][16*j+r] = xacc[j][r];
  }
  __syncthreads();
  if (khalf==0){
    #pragma unroll
    for (int j=0;j<2;j++)
      #pragma unroll
      for (int r=0;r<16;r++)
        xacc[j][r] += Red[qsub][lane][16*j+r];
    const int b = bh>>4, h = bh&15;
    #pragma unroll
    for (int fj=0; fj<2; fj++){
      const int scol = h*4 + fj*2 + (l31>>4);
      const int lpart = ((l31>>3)&1)*32;
      const int epart = l31&7;
      #pragma unroll
      for (int r=0;r<16;r++){
        const int qq = q32*32 + (r&3) + 8*(r>>2) + 4*hi;
        const int row = b*SEQ + qq;
        const size_t addr = ((size_t)(row>>5)*64 + scol)*512 + (lpart + (row&31))*8 + epart;
        xp[addr] = f2b(xacc[fj][r]);
      }
    }
  }
}

// ---------- output projection: LDS-free fragment GEMM, fp32 out ----------
__global__ __launch_bounds__(256,4) void oproj(
    const unsigned short* __restrict__ Xp, const unsigned short* __restrict__ Wop,
    const float* __restrict__ bo, float* __restrict__ out)
{
  const int orig = blockIdx.y*16 + blockIdx.x;
  const int virt = (orig&7)*64 + (orig>>3);
  const int bx = virt&15, by = virt>>4;
  const int mb = by*128, nb = bx*64;

  const int tid = threadIdx.x;
  const int lane = tid&63, wave = tid>>6;
  const int l31 = lane&31, hi = lane>>5;
  f32x16 acc[2] = {};

  const unsigned short* ap  = Xp  + (size_t)((mb>>5) + wave)*32768 + lane*8;
  const unsigned short* b0p = Wop + (size_t)(nb>>5)*32768 + lane*8;
  const unsigned short* b1p = b0p + 32768;

  #pragma unroll 4
  for (int s=0;s<64;s++){
    bf16x8 a  = *(const bf16x8*)(ap  + (size_t)s*512);
    bf16x8 b0 = *(const bf16x8*)(b0p + (size_t)s*512);
    bf16x8 b1 = *(const bf16x8*)(b1p + (size_t)s*512);
    acc[0] = mfma32(a,b0,acc[0]);
    acc[1] = mfma32(a,b1,acc[1]);
  }

  #pragma unroll
  for (int fj=0; fj<2; fj++){
    const int e = nb + 32*fj + l31;
    const float bv_ = bo[e];
    #pragma unroll
    for (int r=0;r<16;r++){
      const int i = mb + 32*wave + (r&3) + 8*(r>>2) + 4*hi;
      out[(size_t)i*DMODEL + e] = acc[fj][r] + bv_;
    }
  }
}

extern "C" void kernel_launch(void* const* d_in, const int* in_sizes, int n_in,
                              void* d_out, int out_size, void* d_ws, size_t ws_size,
                              hipStream_t stream)
{
  const float* q  = (const float*)d_in[0];
  const float* k  = (const float*)d_in[1];
  const float* v  = (const float*)d_in[2];
  const float* A  = (const float*)d_in[3];
  const float* Wq = (const float*)d_in[4];
  const float* bq = (const float*)d_in[5];
  const float* Wk = (const float*)d_in[6];
  const float* bk = (const float*)d_in[7];
  const float* Wv = (const float*)d_in[8];
  const float* bv = (const float*)d_in[9];
  const float* Wo = (const float*)d_in[10];
  const float* bo = (const float*)d_in[11];
  float* out = (float*)d_out;

  // ws (bf16 elems): qh, Kp, Vp, xb, Wp -> 40MB. d_out as scratch:
  //   phase1: Xqp [0,8MB), Xkp [8,16MB)   (consumed by proj)
  //   phase2: Am bf16 [0,8MB)             (written by cvtA after proj, read by attn)
  //   phase3: final fp32 out              (oproj)
  unsigned short* ws = (unsigned short*)d_ws;
  const size_t NE = (size_t)NBATCH*SEQ*DMODEL;   // 4M elements
  unsigned short* qh  = ws;
  unsigned short* Kp  = qh + NE;
  unsigned short* Vp  = Kp + NE;
  unsigned short* xb  = Vp + NE;                 // Xvp before attn, packed-x after
  unsigned short* Wp  = xb + NE;                 // 4 packed weight matrices
  unsigned short* Xqp = (unsigned short*)d_out;
  unsigned short* Xkp = Xqp + NE;
  unsigned short* Am  = (unsigned short*)d_out;  // bf16 2048x2048 = 8MB
  unsigned short* Xvp = xb;

  cvtXpack<<<dim3(128, 1, 3), 256, 0, stream>>>(q, k, v, Xqp, Xkp, Xvp);
  cvtWpack<<<dim3(32, 1, 4), 256, 0, stream>>>(Wq, Wk, Wv, Wo, Wp);
  proj_qkv<<<dim3(8, 32, 3), 256, 0, stream>>>(
      Xqp, Xkp, Xvp, Wp, bq, bk, bv, qh, Kp, Vp);
  cvtA<<<dim3(64, 8), 256, 0, stream>>>(A, Am);
  attn<<<dim3(16, 32), 512, 0, stream>>>(qh, Kp, Vp, Am, xb);
  oproj<<<dim3(16, 32), 256, 0, stream>>>(xb, Wp + (size_t)3*1048576, bo, out);
}

// Round 8
// 141.497 us; speedup vs baseline: 2.5029x; 1.1026x over previous
//
#include <hip/hip_runtime.h>

#define SEQ    2048
#define DMODEL 1024
#define NHEAD  16
#define DHEAD  64
#define NBATCH 2

typedef __bf16 bf16x8 __attribute__((ext_vector_type(8)));
typedef float f32x16 __attribute__((ext_vector_type(16)));
typedef float f32x8 __attribute__((ext_vector_type(8)));
typedef unsigned short ushort8v __attribute__((ext_vector_type(8)));
typedef unsigned int uint2v __attribute__((ext_vector_type(2)));
typedef int int4v __attribute__((ext_vector_type(4)));

static __device__ __forceinline__ unsigned short f2b(float f){
  unsigned int u = __builtin_bit_cast(unsigned int, f);
  u += 0x7fffu + ((u>>16)&1u);            // RNE to bf16
  return (unsigned short)(u>>16);
}
static __device__ __forceinline__ float b2f(unsigned short h){
  unsigned int u = ((unsigned int)h)<<16;
  return __builtin_bit_cast(float, u);
}
static __device__ __forceinline__ f32x16 mfma32(bf16x8 a, bf16x8 b, f32x16 c){
  return __builtin_amdgcn_mfma_f32_32x32x16_bf16(a,b,c,0,0,0);
}
static __device__ __forceinline__ ushort8v cvt8(const float* p){
  float4 f0 = *(const float4*)p;
  float4 f1 = *(const float4*)(p+4);
  ushort8v r;
  r[0]=f2b(f0.x); r[1]=f2b(f0.y); r[2]=f2b(f0.z); r[3]=f2b(f0.w);
  r[4]=f2b(f1.x); r[5]=f2b(f1.y); r[6]=f2b(f1.z); r[7]=f2b(f1.w);
  return r;
}

// ---------- pack X (q,k,v) fp32 -> bf16 MFMA-A-fragment order ----------
// Xp[g][s][lane][8] = X[g*32 + (lane&31)][16*s + 8*(lane>>5) + j]
__global__ __launch_bounds__(256) void cvtXpack(
    const float* __restrict__ q, const float* __restrict__ k, const float* __restrict__ v,
    unsigned short* __restrict__ Xq, unsigned short* __restrict__ Xk, unsigned short* __restrict__ Xv)
{
  const int z = blockIdx.z;
  const float* S = (z==0)? q : (z==1)? k : v;
  unsigned short* D = (z==0)? Xq : (z==1)? Xk : Xv;
  const int g = blockIdx.x;                       // 0..127
  const int wave = threadIdx.x>>6, lane = threadIdx.x&63;
  const int l31 = lane&31, hi = lane>>5;
  const float* src = S + (size_t)(g*32 + l31)*DMODEL + 8*hi + 256*wave;
  unsigned short* dst = D + (size_t)(g*64 + wave*16)*512 + lane*8;
  #pragma unroll
  for (int i=0;i<16;i++)
    *(ushort8v*)(dst + (size_t)i*512) = cvt8(src + 16*i);
}

// ---------- pack Wq,Wk,Wv,Wo fp32 -> bf16 MFMA-B-fragment order ----------
__global__ __launch_bounds__(256) void cvtWpack(
    const float* __restrict__ Wq, const float* __restrict__ Wk,
    const float* __restrict__ Wv, const float* __restrict__ Wo,
    unsigned short* __restrict__ Wp)
{
  const int z = blockIdx.z;
  const float* S = (z==0)? Wq : (z==1)? Wk : (z==2)? Wv : Wo;
  const int g = blockIdx.x;                       // 0..31
  const int wave = threadIdx.x>>6, lane = threadIdx.x&63;
  const int l31 = lane&31, hi = lane>>5;
  const float* src = S + (size_t)(g*32 + l31)*DMODEL + 8*hi + 256*wave;
  unsigned short* dst = Wp + (size_t)((z*32 + g)*64 + wave*16)*512 + lane*8;
  #pragma unroll
  for (int i=0;i<16;i++)
    *(ushort8v*)(dst + (size_t)i*512) = cvt8(src + 16*i);
}

// ---------- A packer (bf16): Am[q32][kt][w][lane][8] = bf16(A[k][q]) ----------
__global__ __launch_bounds__(256) void cvtA(const float* __restrict__ A,
                                            unsigned short* __restrict__ Am){
  const int tid  = threadIdx.x;
  const int lane = tid&63, l31 = lane&31, hi = lane>>5;
  const int q32  = blockIdx.x;                 // 0..63
  const int kt   = blockIdx.y*4 + (tid>>6);    // 0..31
  const int q    = q32*32 + l31;

  unsigned short out8[4][8];
  #pragma unroll
  for (int fi=0; fi<2; fi++){
    #pragma unroll
    for (int mm=0; mm<4; mm++){
      #pragma unroll
      for (int j=0; j<4; j++){
        const int k = kt*64 + 32*fi + 8*mm + 4*hi + j;
        out8[fi*2 + (mm>>1)][(mm&1)*4 + j] = f2b(A[(size_t)k*SEQ + q]);
      }
    }
  }
  unsigned short* dst = Am + ((size_t)(q32*32 + kt)*4)*512 + lane*8;
  #pragma unroll
  for (int w=0; w<4; w++)
    *(ushort8v*)(dst + (size_t)w*512) = *(const ushort8v*)out8[w];
}

// ---------- fused q/k/v projection: LDS-free, barrier-free fragment GEMM ----------
__global__ __launch_bounds__(256,3) void proj_qkv(
    const unsigned short* __restrict__ Xq, const unsigned short* __restrict__ Xk, const unsigned short* __restrict__ Xv,
    const unsigned short* __restrict__ Wp,
    const float* __restrict__ bq, const float* __restrict__ bk, const float* __restrict__ bv,
    unsigned short* __restrict__ qh, unsigned short* __restrict__ Kp, unsigned short* __restrict__ Vp)
{
  const int z = blockIdx.z;
  const unsigned short* X = (z==0)? Xq : (z==1)? Xk : Xv;
  const unsigned short* W = Wp + (size_t)z*1048576;
  const float* bias = (z==0)? bq : (z==1)? bk : bv;
  const float alpha = (z==0)? 0.125f : 1.0f;   // fold 1/sqrt(DK) into qh

  const int orig = blockIdx.y*8 + blockIdx.x;
  const int virt = (orig&7)*32 + (orig>>3);
  const int bx = virt&7, by = virt>>3;
  const int mb = by*128, nb = bx*128;

  const int tid = threadIdx.x;
  const int lane = tid&63, wave = tid>>6;
  const int wr = wave>>1, wc = wave&1, l31 = lane&31, hi = lane>>5;
  f32x16 acc[2][2] = {};

  const unsigned short* a0p = X + (size_t)((mb>>5) + 2*wr)*32768 + lane*8;
  const unsigned short* a1p = a0p + 32768;
  const unsigned short* b0p = W + (size_t)((nb>>5) + 2*wc)*32768 + lane*8;
  const unsigned short* b1p = b0p + 32768;

  #pragma unroll 4
  for (int s=0;s<64;s++){
    bf16x8 a0 = *(const bf16x8*)(a0p + (size_t)s*512);
    bf16x8 a1 = *(const bf16x8*)(a1p + (size_t)s*512);
    bf16x8 b0 = *(const bf16x8*)(b0p + (size_t)s*512);
    bf16x8 b1 = *(const bf16x8*)(b1p + (size_t)s*512);
    acc[0][0] = mfma32(a0,b0,acc[0][0]);
    acc[0][1] = mfma32(a0,b1,acc[0][1]);
    acc[1][0] = mfma32(a1,b0,acc[1][0]);
    acc[1][1] = mfma32(a1,b1,acc[1][1]);
  }

  #pragma unroll
  for (int fj=0; fj<2; fj++){
    const int e = nb + 64*wc + 32*fj + l31;
    const float bv_ = bias[e];
    const int hh = e>>6, dk = e&63;
    #pragma unroll
    for (int fi=0; fi<2; fi++){
      #pragma unroll
      for (int r=0;r<16;r++){
        const int i = mb + 64*wr + 32*fi + (r&3) + 8*(r>>2) + 4*hi;
        const int bb = i>>11, ss = i&(SEQ-1);
        const int bhh = bb*NHEAD + hh;
        const unsigned short val = f2b((acc[fi][fj][r] + bv_)*alpha);
        if (z==0){
          qh[((size_t)bhh*SEQ + ss)*DHEAD + dk] = val;
        } else if (z==1){
          const size_t addr = (((size_t)(bhh*64 + (ss>>5))*4 + (dk>>4))*64
                               + ((dk>>3)&1)*32 + (ss&31))*8 + (dk&7);
          Kp[addr] = val;
        } else {
          const size_t addr = ((((size_t)(bhh*32 + (ss>>6))*4 + ((ss>>4)&3))*2
                               + (dk>>5))*64 + ((ss>>3)&1)*32 + (dk&31))*8 + (ss&7);
          Vp[addr] = val;
        }
      }
    }
  }
}

// ---------- fused masked attention: x = (Qh Kh^T ∘ A^T) Vh ----------
// 512 threads = 8 waves = 4 q32 x 2 khalf; 128 q-rows/block.
// One-iteration-deep register prefetch of K and A (ping-pong, 2x unrolled);
// V loaded at iteration top so QK^T+mask covers its L2 latency.
__global__ __launch_bounds__(512,2) void attn(
    const unsigned short* __restrict__ qh, const unsigned short* __restrict__ Kp,
    const unsigned short* __restrict__ Vp, const unsigned short* __restrict__ Am,
    unsigned short* __restrict__ xp)
{
  // 512 blocks: xcd = orig&7 owns bh in [xcd*4, xcd*4+4)
  const int orig = blockIdx.y*16 + blockIdx.x;
  const int xcd = orig&7, within = orig>>3;
  const int bh   = xcd*4 + (within>>4);   // 0..31
  const int qblk = within&15;             // 0..15 (128 q-rows each)

  const int tid  = threadIdx.x;
  const int lane = tid&63, wave = tid>>6;
  const int qsub = wave&3, khalf = wave>>2;
  const int l31 = lane&31, hi = lane>>5;

  const int q32  = qblk*4 + qsub;
  const int qrow = q32*32 + l31;
  const unsigned short* qp = qh + ((size_t)bh*SEQ + qrow)*DHEAD;
  bf16x8 Qf[4];
  #pragma unroll
  for (int t=0;t<4;t++) Qf[t] = *(const bf16x8*)(qp + 16*t + 8*hi);

  f32x16 xacc[2] = {};

  const unsigned short* kpb = Kp + ((size_t)bh*64)*2048 + lane*8;   // [k32][s][lane][8]
  const unsigned short* vpb = Vp + ((size_t)bh*32)*4096 + lane*8;   // [k64][s2][dhalf][lane][8]
  const unsigned short* apb = Am + ((size_t)q32*32)*2048 + lane*8;  // [kt][w][lane][8] bf16

  bf16x8 Ka[8], Kb[8];
  ushort8v Aa[4], Ab[4];

  #define LOADK(DST, KT) { \
    const unsigned short* _kp = kpb + (size_t)((KT)*2)*2048; \
    _Pragma("unroll") \
    for (int s=0;s<8;s++) DST[s] = *(const bf16x8*)(_kp + (size_t)s*512); }
  #define LOADA(DST, KT) { \
    const unsigned short* _ap = apb + (size_t)(KT)*2048; \
    _Pragma("unroll") \
    for (int w=0;w<4;w++) DST[w] = *(const ushort8v*)(_ap + (size_t)w*512); }

  LOADK(Ka, khalf*16);
  LOADA(Aa, khalf*16);

  #define BODY(T, KR, AR, KN, AN, TN) { \
    const int _kt = khalf*16 + (T); \
    const unsigned short* _vp = vpb + (size_t)_kt*4096; \
    bf16x8 Vr[8]; \
    _Pragma("unroll") \
    for (int s=0;s<8;s++) Vr[s] = *(const bf16x8*)(_vp + (size_t)s*512); \
    LOADK(KN, khalf*16 + (TN)); \
    LOADA(AN, khalf*16 + (TN)); \
    unsigned int wv[2][4], xv[2][4]; \
    _Pragma("unroll") \
    for (int fi=0; fi<2; fi++){ \
      f32x16 sacc = {}; \
      _Pragma("unroll") \
      for (int s=0;s<4;s++) \
        sacc = mfma32(KR[fi*4+s], Qf[s], sacc); \
      ushort8v a80 = AR[fi*2+0], a81 = AR[fi*2+1]; \
      _Pragma("unroll") \
      for (int mm=0; mm<4; mm++){ \
        const int b0 = (mm&1)*4, rb2 = 4*mm; \
        float p0 = sacc[rb2+0]*((mm>>1)? b2f(a81[b0+0]) : b2f(a80[b0+0])); \
        float p1 = sacc[rb2+1]*((mm>>1)? b2f(a81[b0+1]) : b2f(a80[b0+1])); \
        float p2 = sacc[rb2+2]*((mm>>1)? b2f(a81[b0+2]) : b2f(a80[b0+2])); \
        float p3 = sacc[rb2+3]*((mm>>1)? b2f(a81[b0+3]) : b2f(a80[b0+3])); \
        asm("v_cvt_pk_bf16_f32 %0, %1, %2" : "=v"(wv[fi][mm]) : "v"(p0), "v"(p1)); \
        asm("v_cvt_pk_bf16_f32 %0, %1, %2" : "=v"(xv[fi][mm]) : "v"(p2), "v"(p3)); \
      } \
    } \
    __builtin_amdgcn_s_setprio(1); \
    _Pragma("unroll") \
    for (int s2=0; s2<4; s2++){ \
      const int fi = s2>>1, sl = s2&1; \
      uint2v rw = __builtin_amdgcn_permlane32_swap(wv[fi][2*sl], wv[fi][2*sl+1], false, false); \
      uint2v rx = __builtin_amdgcn_permlane32_swap(xv[fi][2*sl], xv[fi][2*sl+1], false, false); \
      int4v av; av.x = (int)rw[0]; av.y = (int)rx[0]; av.z = (int)rw[1]; av.w = (int)rx[1]; \
      bf16x8 pa = __builtin_bit_cast(bf16x8, av); \
      xacc[0] = mfma32(pa, Vr[s2*2+0], xacc[0]); \
      xacc[1] = mfma32(pa, Vr[s2*2+1], xacc[1]); \
    } \
    __builtin_amdgcn_s_setprio(0); }

  #pragma unroll 1
  for (int tt=0; tt<8; tt++){
    const int t0 = 2*tt, t1 = 2*tt+1;
    BODY(t0, Ka, Aa, Kb, Ab, t1);
    BODY(t1, Kb, Ab, Ka, Aa, (t1+1)&15);
  }
  #undef BODY
  #undef LOADK
  #undef LOADA

  // cross-wave split-K reduction (single barrier)
  __shared__ float Red[4][64][33];
  if (khalf==1){
    #pragma unroll
    for (int j=0;j<2;j++)
      #pragma unroll
      for (int r=0;r<16;r++)
        Red[qsub][lane][16*j+r] = xacc[j][r];
  }
  __syncthreads();
  if (khalf==0){
    #pragma unroll
    for (int j=0;j<2;j++)
      #pragma unroll
      for (int r=0;r<16;r++)
        xacc[j][r] += Red[qsub][lane][16*j+r];
    const int b = bh>>4, h = bh&15;
    #pragma unroll
    for (int fj=0; fj<2; fj++){
      const int scol = h*4 + fj*2 + (l31>>4);
      const int lpart = ((l31>>3)&1)*32;
      const int epart = l31&7;
      #pragma unroll
      for (int r=0;r<16;r++){
        const int qq = q32*32 + (r&3) + 8*(r>>2) + 4*hi;
        const int row = b*SEQ + qq;
        const size_t addr = ((size_t)(row>>5)*64 + scol)*512 + (lpart + (row&31))*8 + epart;
        xp[addr] = f2b(xacc[fj][r]);
      }
    }
  }
}

// ---------- output projection: LDS-free fragment GEMM, fp32 out ----------
__global__ __launch_bounds__(256,4) void oproj(
    const unsigned short* __restrict__ Xp, const unsigned short* __restrict__ Wop,
    const float* __restrict__ bo, float* __restrict__ out)
{
  const int orig = blockIdx.y*16 + blockIdx.x;
  const int virt = (orig&7)*64 + (orig>>3);
  const int bx = virt&15, by = virt>>4;
  const int mb = by*128, nb = bx*64;

  const int tid = threadIdx.x;
  const int lane = tid&63, wave = tid>>6;
  const int l31 = lane&31, hi = lane>>5;
  f32x16 acc[2] = {};

  const unsigned short* ap  = Xp  + (size_t)((mb>>5) + wave)*32768 + lane*8;
  const unsigned short* b0p = Wop + (size_t)(nb>>5)*32768 + lane*8;
  const unsigned short* b1p = b0p + 32768;

  #pragma unroll 4
  for (int s=0;s<64;s++){
    bf16x8 a  = *(const bf16x8*)(ap  + (size_t)s*512);
    bf16x8 b0 = *(const bf16x8*)(b0p + (size_t)s*512);
    bf16x8 b1 = *(const bf16x8*)(b1p + (size_t)s*512);
    acc[0] = mfma32(a,b0,acc[0]);
    acc[1] = mfma32(a,b1,acc[1]);
  }

  #pragma unroll
  for (int fj=0; fj<2; fj++){
    const int e = nb + 32*fj + l31;
    const float bv_ = bo[e];
    #pragma unroll
    for (int r=0;r<16;r++){
      const int i = mb + 32*wave + (r&3) + 8*(r>>2) + 4*hi;
      out[(size_t)i*DMODEL + e] = acc[fj][r] + bv_;
    }
  }
}

extern "C" void kernel_launch(void* const* d_in, const int* in_sizes, int n_in,
                              void* d_out, int out_size, void* d_ws, size_t ws_size,
                              hipStream_t stream)
{
  const float* q  = (const float*)d_in[0];
  const float* k  = (const float*)d_in[1];
  const float* v  = (const float*)d_in[2];
  const float* A  = (const float*)d_in[3];
  const float* Wq = (const float*)d_in[4];
  const float* bq = (const float*)d_in[5];
  const float* Wk = (const float*)d_in[6];
  const float* bk = (const float*)d_in[7];
  const float* Wv = (const float*)d_in[8];
  const float* bv = (const float*)d_in[9];
  const float* Wo = (const float*)d_in[10];
  const float* bo = (const float*)d_in[11];
  float* out = (float*)d_out;

  // ws (bf16 elems): qh, Kp, Vp, xb, Wp -> 40MB. d_out as scratch:
  //   phase1: Xqp [0,8MB), Xkp [8,16MB)   (consumed by proj)
  //   phase2: Am bf16 [0,8MB)             (written by cvtA after proj, read by attn)
  //   phase3: final fp32 out              (oproj)
  unsigned short* ws = (unsigned short*)d_ws;
  const size_t NE = (size_t)NBATCH*SEQ*DMODEL;   // 4M elements
  unsigned short* qh  = ws;
  unsigned short* Kp  = qh + NE;
  unsigned short* Vp  = Kp + NE;
  unsigned short* xb  = Vp + NE;                 // Xvp before attn, packed-x after
  unsigned short* Wp  = xb + NE;                 // 4 packed weight matrices
  unsigned short* Xqp = (unsigned short*)d_out;
  unsigned short* Xkp = Xqp + NE;
  unsigned short* Am  = (unsigned short*)d_out;  // bf16 2048x2048 = 8MB
  unsigned short* Xvp = xb;

  cvtXpack<<<dim3(128, 1, 3), 256, 0, stream>>>(q, k, v, Xqp, Xkp, Xvp);
  cvtWpack<<<dim3(32, 1, 4), 256, 0, stream>>>(Wq, Wk, Wv, Wo, Wp);
  proj_qkv<<<dim3(8, 32, 3), 256, 0, stream>>>(
      Xqp, Xkp, Xvp, Wp, bq, bk, bv, qh, Kp, Vp);
  cvtA<<<dim3(64, 8), 256, 0, stream>>>(A, Am);
  attn<<<dim3(16, 32), 512, 0, stream>>>(qh, Kp, Vp, Am, xb);
  oproj<<<dim3(16, 32), 256, 0, stream>>>(xb, Wp + (size_t)3*1048576, bo, out);
}